// Round 9
// baseline (1002.824 us; speedup 1.0000x reference)
//
#include <hip/hip_runtime.h>
#include <math.h>

// ---- problem constants ----
#define Dm   512
#define Nn_  256
#define Bv   2
#define NBLK 6
#define BBAT 12            // NBLK*Bv
#define NT   3072          // BBAT*Nn_
#define NH   8
#define DH   64
#define DFF  1365
#define DFF2 2730
#define KFF  1408          // DFF padded to mult of 32 (ffv K)
#define NFF  2816          // DFF2 padded to mult of 128 (ffk N)
#define MMAX 42            // max pooled-context messages
#define EPSR 1.1920929e-07f

typedef _Float16 h16;
typedef h16  v8h  __attribute__((ext_vector_type(8)));
typedef float v4f __attribute__((ext_vector_type(4)));

__device__ inline h16 f2h(float v) { return (h16)v; }   // v_cvt_f16_f32, RNE

__device__ inline void glds16(const void* g, void* l) {
    __builtin_amdgcn_global_load_lds((const __attribute__((address_space(1))) void*)g,
                                     (__attribute__((address_space(3))) void*)l, 16, 0, 0);
}

// =====================================================================
// Multi-GEMM dispatcher, fp16 3-term compensated.
//   A = Ah + Al (fp16 planes, lo at +Apl); W = Wh + Wl (lo at +Wpl).
//   acc += Ah*Wh + Ah*Wl + Al*Wh   (drops only Al*Wl ~ 2^-24 rel)
// A-fragments: wave-private -> loaded GLOBAL->REGISTERS (reg ping-pong,
// no LDS). W tiles: LDS, double-buffered (32 KB total) -> ~3 blocks/CU.
// K-loop unrolled x2 (all K % 64 == 0).
// modes: 0 fp32 C; 1 fp16 hi/lo Cbf; 2 both; 3 fp32 pooled-ctx remap;
//        4 attention KV split: col<512 -> Cbf (K, [row][512] hi/lo),
//          col>=512 -> (h16*)C as V^T [bat*8+head][dim][j] hi/lo.
// =====================================================================
struct GDesc {
    const h16* A;
    const h16* W;
    const float* bias;
    float* C;
    h16* Cbf;
    long Apl, Wpl, bfpl;
    int lda, ldw, ldc, Nd, mbase, K, mode, nbx;
};

template <int BM>
__global__ __launch_bounds__(256) void mega_gemm(GDesc d0, GDesc d1, GDesc d2,
                                                 int n0, int n01)
{
    constexpr int MI = BM / 32;          // 16-row acc tiles per wave (m dir)
    constexpr int WBUF = 8192;           // h16 per W buffer (Wh 4096 | Wl 4096)
    __shared__ h16 lds[2 * WBUF];        // 32 KB

    GDesc d; int lb = blockIdx.x;
    if (lb < n0) d = d0;
    else if (lb < n01) { d = d1; lb -= n0; }
    else { d = d2; lb -= n01; }
    const int bx = lb % d.nbx;
    const int by = lb / d.nbx;

    const int tid = threadIdx.x;
    const int wid = tid >> 6;
    const int lane = tid & 63;
    const int wm = wid >> 1, wn = wid & 1;
    const int row16 = lane & 15, quad = lane >> 4;
    const long i0 = (long)bx * BM;
    const long j0 = (long)by * 128;
    const int l4 = lane >> 2;                      // row within 16-row segment
    const int l2s = ((lane & 3) ^ (l4 & 3)) * 8;   // swizzled k-chunk src offset
    const int ksw = (quad ^ (row16 & 3)) * 8;      // matching fragment slot

    // A fragment base: lane (row16, quad) reads 16 B at row i0+wm*(BM/2)+mi*16+row16
    const h16* aBase = d.A + (i0 + wm * (BM / 2) + row16) * (long)d.lda + quad * 8;

    auto stageW = [&](int k0, h16* buf) {
        #pragma unroll
        for (int s = 0; s < 4; ++s) {
            const int sg = wid * 4 + s;            // 16 segments: Wh 0-7, Wl 8-15
            const h16* src;
            int dst;
            if (sg < 8) {
                src = d.W + (j0 + sg * 16 + l4) * (long)d.ldw + k0 + l2s;
                dst = sg * 512;
            } else {
                const int r = sg - 8;
                src = d.W + d.Wpl + (j0 + r * 16 + l4) * (long)d.ldw + k0 + l2s;
                dst = 4096 + r * 512;
            }
            glds16(src, &buf[dst]);
        }
    };

    v8h afA[MI], alA[MI], afB[MI], alB[MI];
    auto loadA = [&](int k0, v8h* af, v8h* al) {
        #pragma unroll
        for (int mi = 0; mi < MI; ++mi) {
            const h16* ap = aBase + (long)mi * 16 * d.lda + k0;
            af[mi] = *(const v8h*)ap;
            al[mi] = *(const v8h*)(ap + d.Apl);
        }
    };

    v4f acc[MI][4];
    #pragma unroll
    for (int a = 0; a < MI; ++a)
        #pragma unroll
        for (int b = 0; b < 4; ++b) acc[a][b] = (v4f){0.f, 0.f, 0.f, 0.f};

    auto compute = [&](const h16* cbuf, const v8h* af, const v8h* al) {
        #pragma unroll
        for (int nj = 0; nj < 4; ++nj) {
            const int boff = (wn * 64 + nj * 16 + row16) * 32 + ksw;
            v8h bh = *(const v8h*)&cbuf[boff];
            v8h bl = *(const v8h*)&cbuf[4096 + boff];
            #pragma unroll
            for (int mi = 0; mi < MI; ++mi) {
                acc[mi][nj] = __builtin_amdgcn_mfma_f32_16x16x32_f16(af[mi], bh, acc[mi][nj], 0, 0, 0);
                acc[mi][nj] = __builtin_amdgcn_mfma_f32_16x16x32_f16(af[mi], bl, acc[mi][nj], 0, 0, 0);
                acc[mi][nj] = __builtin_amdgcn_mfma_f32_16x16x32_f16(al[mi], bh, acc[mi][nj], 0, 0, 0);
            }
        }
    };

    loadA(0, afA, alA);
    stageW(0, lds);
    for (int k0 = 0; k0 < d.K; k0 += 64) {
        __syncthreads();                       // stageW(k0) drained; buf1 free
        stageW(k0 + 32, &lds[WBUF]);           // K % 64 == 0 -> always valid
        loadA(k0 + 32, afB, alB);
        compute(lds, afA, alA);
        __syncthreads();                       // stageW(k0+32) drained; buf0 free
        if (k0 + 64 < d.K) {
            stageW(k0 + 64, lds);
            loadA(k0 + 64, afA, alA);
        }
        compute(&lds[WBUF], afB, alB);
    }

    // C/D layout: col = lane&15 (W side), row = quad*4 + reg (A side)
    #pragma unroll
    for (int nj = 0; nj < 4; ++nj) {
        const int col = (int)j0 + wn * 64 + nj * 16 + row16;
        if (col < d.Nd) {
            const float bv = d.bias ? d.bias[col] : 0.f;
            #pragma unroll
            for (int mi = 0; mi < MI; ++mi) {
                #pragma unroll
                for (int r = 0; r < 4; ++r) {
                    const long row = i0 + wm * (BM / 2) + mi * 16 + quad * 4 + r;
                    const float v = acc[mi][nj][r] + bv;
                    if (d.mode == 0) {
                        d.C[row * (long)d.ldc + col] = v;
                    } else if (d.mode == 1) {
                        const long idx = row * (long)d.ldc + col;
                        const h16 hi = f2h(v);
                        d.Cbf[idx] = hi; d.Cbf[idx + d.bfpl] = f2h(v - (float)hi);
                    } else if (d.mode == 2) {
                        const long idx = row * (long)d.ldc + col;
                        d.C[idx] = v;
                        const h16 hi = f2h(v);
                        d.Cbf[idx] = hi; d.Cbf[idx + d.bfpl] = f2h(v - (float)hi);
                    } else if (d.mode == 3) {
                        const int srel = (int)(row / 3072);
                        const int rr = (int)row - srel * 3072;
                        const long orow = (long)(rr & 511) * MMAX + d.mbase + srel * 6 + (rr >> 9);
                        d.C[orow * 1024 + col] = v;
                    } else {
                        const h16 hi = f2h(v);
                        const h16 lo = f2h(v - (float)hi);
                        if (col < 512) {
                            const long idx = row * 512 + col;
                            d.Cbf[idx] = hi; d.Cbf[idx + d.bfpl] = lo;
                        } else {
                            const int c = col - 512;
                            const int bh_ = ((int)(row >> 8)) * 8 + (c >> 6);
                            const long idx = (((long)bh_ * 64 + (c & 63)) << 8) + (row & 255);
                            h16* vtp = (h16*)d.C;
                            vtp[idx] = hi; vtp[idx + d.bfpl] = lo;
                        }
                    }
                }
            }
        }
    }
}

// =====================================================================
// fp32 -> fp16 hi/lo planes, with zero-padding
// =====================================================================
__global__ void cvt_hilo(const float* __restrict__ x, int Ms, int Ks, int Kp,
                         h16* __restrict__ y, long plane, int total)
{
    const int idx = blockIdx.x * 256 + threadIdx.x;
    if (idx >= total) return;
    const int row = idx / Kp;
    const int col = idx - row * Kp;
    const float v = (row < Ms && col < Ks) ? x[(long)row * Ks + col] : 0.f;
    const h16 hi = f2h(v);
    y[idx] = hi;
    y[idx + plane] = f2h(v - (float)hi);
}

// =====================================================================
// Triple RMSNorm: same row -> same rsqrt; writes 3 fp16 hi/lo outputs.
// =====================================================================
__global__ __launch_bounds__(256) void rmsnorm3_bf(
    const float* __restrict__ x,
    const float* __restrict__ w0, const float* __restrict__ w1,
    const float* __restrict__ w2,
    h16* __restrict__ y0, h16* __restrict__ y1,
    h16* __restrict__ y2, long plane)
{
    const int r = blockIdx.x;
    const float* xr = x + (long)r * Dm;
    const int t = threadIdx.x;
    const float a = xr[t];
    const float b = xr[t + 256];
    float ss = a * a + b * b;
    #pragma unroll
    for (int off = 32; off > 0; off >>= 1) ss += __shfl_xor(ss, off, 64);
    __shared__ float w4[4];
    if ((t & 63) == 0) w4[t >> 6] = ss;
    __syncthreads();
    const float rs = rsqrtf((w4[0] + w4[1] + w4[2] + w4[3]) * (1.f / 512.f) + EPSR);
    const float na = a * rs, nb = b * rs;
    const long ia = (long)r * Dm + t, ib = ia + 256;
    h16 h;
    float v;
    v = na * w0[t];       h = f2h(v); y0[ia] = h; y0[ia + plane] = f2h(v - (float)h);
    v = nb * w0[t + 256]; h = f2h(v); y0[ib] = h; y0[ib + plane] = f2h(v - (float)h);
    v = na * w1[t];       h = f2h(v); y1[ia] = h; y1[ia + plane] = f2h(v - (float)h);
    v = nb * w1[t + 256]; h = f2h(v); y1[ib] = h; y1[ib + plane] = f2h(v - (float)h);
    v = na * w2[t];       h = f2h(v); y2[ia] = h; y2[ia + plane] = f2h(v - (float)h);
    v = nb * w2[t + 256]; h = f2h(v); y2[ib] = h; y2[ib + plane] = f2h(v - (float)h);
}

// =====================================================================
// GLU * exact GELU; h is [NT, 2816]-strided fp32; output fp16 hi/lo, KFF cols.
// =====================================================================
__global__ __launch_bounds__(256) void glu_gelu_bf(
    const float* __restrict__ h, h16* __restrict__ y, long plane)
{
    const int r = blockIdx.x;
    const float* row = h + (long)r * NFF;
    for (int c = threadIdx.x; c < KFF; c += 256) {
        float v = 0.f;
        if (c < DFF) {
            const float sim = row[c];
            const float g = row[c + DFF];
            v = sim * (0.5f * g * (1.f + erff(g * 0.70710678118654752440f)));
        }
        const long idx = (long)r * KFF + c;
        const h16 hi = f2h(v);
        y[idx] = hi;
        y[idx + plane] = f2h(v - (float)hi);
    }
}

// =====================================================================
// MFMA flash self-attention. Grid = bat(12) x head(8) x qtile(4); 256 thr.
// =====================================================================
__global__ __launch_bounds__(256) void attn_self_mfma(
    const h16* __restrict__ qhl, const h16* __restrict__ khl,
    const h16* __restrict__ vtb, long pl, h16* __restrict__ outbf)
{
    __shared__ h16 kh[4096], kl[4096], vh[4096], vl[4096];
    __shared__ h16 pH[4 * 1024], pL[4 * 1024];

    const int bat = blockIdx.x >> 5;
    const int head = (blockIdx.x >> 2) & 7;
    const int qc = blockIdx.x & 3;
    const int t = threadIdx.x;
    const int w = t >> 6, lane = t & 63;
    const int row16 = lane & 15, quad = lane >> 4;

    v8h qh[2], ql[2];
    {
        const long qrow = (long)bat * 256 + qc * 64 + w * 16 + row16;
        const h16* qp = qhl + qrow * 512 + head * 64 + quad * 8;
        qh[0] = *(const v8h*)qp;        qh[1] = *(const v8h*)(qp + 32);
        ql[0] = *(const v8h*)(qp + pl); ql[1] = *(const v8h*)(qp + pl + 32);
    }

    v4f O[4];
    #pragma unroll
    for (int i = 0; i < 4; ++i) O[i] = (v4f){0.f, 0.f, 0.f, 0.f};
    float m[4] = {-1e30f, -1e30f, -1e30f, -1e30f};
    float l[4] = {0.f, 0.f, 0.f, 0.f};

    const int sj = t >> 3;
    const int sc = t & 7;
    const long kbase = ((long)bat * 256) * 512 + head * 64;
    const long vbase = ((long)(bat * 8 + head) * 64) << 8;

    for (int jc = 0; jc < 256; jc += 64) {
        __syncthreads();
        #pragma unroll
        for (int rep = 0; rep < 2; ++rep) {
            const int row = sj + rep * 32;
            const int dsw = row * 64 + ((sc ^ (row & 7)) * 8);
            const h16* ks = khl + kbase + (long)(jc + row) * 512 + sc * 8;
            const h16* vs = vtb + vbase + ((long)row << 8) + jc + sc * 8;
            *(v8h*)&kh[dsw] = *(const v8h*)ks;
            *(v8h*)&kl[dsw] = *(const v8h*)(ks + pl);
            *(v8h*)&vh[dsw] = *(const v8h*)vs;
            *(v8h*)&vl[dsw] = *(const v8h*)(vs + pl);
        }
        __syncthreads();

        v4f S[4];
        #pragma unroll
        for (int i = 0; i < 4; ++i) S[i] = (v4f){0.f, 0.f, 0.f, 0.f};
        #pragma unroll
        for (int kk = 0; kk < 2; ++kk) {
            #pragma unroll
            for (int tile = 0; tile < 4; ++tile) {
                const int off = (tile * 16 + row16) * 64 + (((kk * 4 + quad) ^ (row16 & 7)) * 8);
                v8h bh = *(const v8h*)&kh[off];
                v8h bl = *(const v8h*)&kl[off];
                S[tile] = __builtin_amdgcn_mfma_f32_16x16x32_f16(qh[kk], bh, S[tile], 0, 0, 0);
                S[tile] = __builtin_amdgcn_mfma_f32_16x16x32_f16(qh[kk], bl, S[tile], 0, 0, 0);
                S[tile] = __builtin_amdgcn_mfma_f32_16x16x32_f16(ql[kk], bh, S[tile], 0, 0, 0);
            }
        }

        float mc[4], sums[4], alpha[4];
        #pragma unroll
        for (int r = 0; r < 4; ++r) {
            float v = fmaxf(fmaxf(S[0][r], S[1][r]), fmaxf(S[2][r], S[3][r]));
            v = fmaxf(v, __shfl_xor(v, 1, 64));
            v = fmaxf(v, __shfl_xor(v, 2, 64));
            v = fmaxf(v, __shfl_xor(v, 4, 64));
            v = fmaxf(v, __shfl_xor(v, 8, 64));
            mc[r] = v;
        }
        #pragma unroll
        for (int r = 0; r < 4; ++r) {
            const float mn = fmaxf(m[r], mc[r]);
            alpha[r] = __expf(m[r] - mn);
            m[r] = mn;
            sums[r] = 0.f;
        }
        #pragma unroll
        for (int tile = 0; tile < 4; ++tile) {
            #pragma unroll
            for (int r = 0; r < 4; ++r) {
                const float p = __expf(S[tile][r] - m[r]);
                S[tile][r] = p;
                sums[r] += p;
            }
        }
        #pragma unroll
        for (int r = 0; r < 4; ++r) {
            float v = sums[r];
            v += __shfl_xor(v, 1, 64);
            v += __shfl_xor(v, 2, 64);
            v += __shfl_xor(v, 4, 64);
            v += __shfl_xor(v, 8, 64);
            l[r] = l[r] * alpha[r] + v;
        }
        #pragma unroll
        for (int tile = 0; tile < 4; ++tile)
            #pragma unroll
            for (int r = 0; r < 4; ++r) O[tile][r] *= alpha[r];

        #pragma unroll
        for (int tile = 0; tile < 4; ++tile) {
            const int chunkcol = tile * 2 + (row16 >> 3);
            #pragma unroll
            for (int r = 0; r < 4; ++r) {
                const int prow = quad * 4 + r;
                const int addr = w * 1024 + prow * 64 +
                                 ((chunkcol ^ (prow & 7)) * 8) + (row16 & 7);
                const float p = S[tile][r];
                const h16 hi = f2h(p);
                pH[addr] = hi;
                pL[addr] = f2h(p - (float)hi);
            }
        }

        #pragma unroll
        for (int kk = 0; kk < 2; ++kk) {
            const int poff = w * 1024 + row16 * 64 + (((kk * 4 + quad) ^ (row16 & 7)) * 8);
            v8h pa = *(const v8h*)&pH[poff];
            v8h pb = *(const v8h*)&pL[poff];
            #pragma unroll
            for (int tile = 0; tile < 4; ++tile) {
                const int off = (tile * 16 + row16) * 64 + (((kk * 4 + quad) ^ (row16 & 7)) * 8);
                v8h vbh = *(const v8h*)&vh[off];
                v8h vbl = *(const v8h*)&vl[off];
                O[tile] = __builtin_amdgcn_mfma_f32_16x16x32_f16(pa, vbh, O[tile], 0, 0, 0);
                O[tile] = __builtin_amdgcn_mfma_f32_16x16x32_f16(pa, vbl, O[tile], 0, 0, 0);
                O[tile] = __builtin_amdgcn_mfma_f32_16x16x32_f16(pb, vbh, O[tile], 0, 0, 0);
            }
        }
    }

    #pragma unroll
    for (int tile = 0; tile < 4; ++tile) {
        const int dim = tile * 16 + row16;
        #pragma unroll
        for (int r = 0; r < 4; ++r) {
            const long grow = (long)bat * 256 + qc * 64 + w * 16 + quad * 4 + r;
            const float v = O[tile][r] / l[r];
            const long idx = grow * 512 + head * 64 + dim;
            const h16 hi = f2h(v);
            outbf[idx] = hi;
            outbf[idx + pl] = f2h(v - (float)hi);
        }
    }
}

// =====================================================================
// Pooled attention, lane-per-m: block per (rb, head), 384 thr = 6 waves.
// =====================================================================
template <int M>
__global__ __launch_bounds__(384) void attn_pool_kernel(
    const float* __restrict__ qb, const float* __restrict__ kvc2,
    h16* __restrict__ outbf, long plane)
{
    const int rb = blockIdx.x >> 3;
    const int h = blockIdx.x & 7;
    __shared__ float k_lds[M * 66];
    __shared__ float v_lds[M * 66];
    __shared__ float q_lds[6 * 64];
    __shared__ float p_lds[6 * 64];
    const int t = threadIdx.x;
    const int cb = rb >> 8, nn = rb & 255;

    for (int idx = t; idx < M * 64; idx += 384) {
        const int m = idx >> 6, d = idx & 63;
        const long base = ((long)rb * MMAX + m) * 1024 + h * DH + d;
        k_lds[m * 66 + d] = kvc2[base];
        v_lds[m * 66 + d] = kvc2[base + 512];
    }
    {
        const int w = t >> 6, dd = t & 63;
        const long iq = (long)cb * 1536 + nn + w * 256;
        q_lds[t] = qb[iq * Dm + h * DH + dd];
    }
    __syncthreads();

    const int w = t >> 6;
    const int lane = t & 63;
    float s = -1e30f;
    if (lane < M) {
        s = 0.f;
        const float* kr = &k_lds[lane * 66];
        const float* qr = &q_lds[w * 64];
        #pragma unroll
        for (int dd = 0; dd < 64; dd += 2) {
            s = fmaf(qr[dd], kr[dd], s);
            s = fmaf(qr[dd + 1], kr[dd + 1], s);
        }
    }
    float mx = s;
    #pragma unroll
    for (int off = 32; off > 0; off >>= 1) mx = fmaxf(mx, __shfl_xor(mx, off, 64));
    const float p = __expf(s - mx);
    float l = p;
    #pragma unroll
    for (int off = 32; off > 0; off >>= 1) l += __shfl_xor(l, off, 64);
    p_lds[w * 64 + lane] = p / l;

    float o = 0.f;
    const float* pr = &p_lds[w * 64];
    #pragma unroll
    for (int m = 0; m < M; ++m)
        o = fmaf(pr[m], v_lds[m * 66 + lane], o);

    const long iq = (long)cb * 1536 + nn + w * 256;
    const long oidx = iq * Dm + h * DH + lane;
    const h16 hi = f2h(o);
    outbf[oidx] = hi;
    outbf[oidx + plane] = f2h(o - (float)hi);
}

// =====================================================================
// Broadcast tokens [2,256,512] -> tokens fp32, tokbf hi/lo, msgs set0
// =====================================================================
__global__ void replicate_kernel(const float* __restrict__ src,
                                 float* __restrict__ tokens,
                                 h16* __restrict__ tokbf, long tpl,
                                 h16* __restrict__ msg0, long mpl)
{
    const int idx = blockIdx.x * blockDim.x + threadIdx.x;
    if (idx >= NT * Dm) return;
    const float v = src[idx & (Bv * Nn_ * Dm - 1)];
    tokens[idx] = v;
    const h16 hi = f2h(v);
    const h16 lo = f2h(v - (float)hi);
    tokbf[idx] = hi; tokbf[idx + tpl] = lo;
    msg0[idx] = hi; msg0[idx + mpl] = lo;
}

// =====================================================================
extern "C" void kernel_launch(void* const* d_in, const int* in_sizes, int n_in,
                              void* d_out, int out_size, void* d_ws, size_t ws_size,
                              hipStream_t stream)
{
    const float* tok_in       = (const float*)d_in[0];
    const float* attn_norm_w  = (const float*)d_in[1];
    const float* attn_wq      = (const float*)d_in[2];
    const float* attn_wkv     = (const float*)d_in[3];
    const float* attn_wo      = (const float*)d_in[4];
    const float* ff_norm_w    = (const float*)d_in[5];
    const float* ff_keys_w    = (const float*)d_in[6];
    const float* ff_keys_b    = (const float*)d_in[7];
    const float* ff_values_w  = (const float*)d_in[8];
    const float* ff_values_b  = (const float*)d_in[9];
    const float* res_norm_w   = (const float*)d_in[10];
    const float* res_wq       = (const float*)d_in[11];
    const float* res_wkv      = (const float*)d_in[12];
    const float* res_wo       = (const float*)d_in[13];

    float* ws = (float*)d_ws;
    float* kvc2   = ws;                                  // 512*42*1024
    float* tokens = kvc2 + 512L * MMAX * 1024;           // NT*512
    float* qbuf   = tokens + (long)NT * Dm;              // NT*512 (pool q)
    float* hbuf   = qbuf + (long)NT * Dm;                // NT*2816

    h16* us = (h16*)(hbuf + (long)NT * NFF);
    const long apl = (long)NT * Dm;          // activation plane
    const long mpl = 7L * NT * Dm;           // msgs plane (7 sets)
    const long hpl = (long)NT * KFF;
    const long w1 = 512L * 512, w2 = 1024L * 512, w3 = (long)NFF * 512, w4 = 512L * KFF;
    h16* msgs_bf = us; us += 2 * mpl;
    h16* tokbf   = us; us += 2 * apl;
    h16* xa      = us; us += 2 * apl;
    h16* xf      = us; us += 2 * apl;
    h16* xr      = us; us += 2 * apl;
    h16* abf     = us; us += 2 * apl;
    h16* hbf     = us; us += 2 * hpl;
    h16* qhl     = us; us += 2 * apl;   // self-attn Q hi/lo
    h16* khl     = us; us += 2 * apl;   // self-attn K hi/lo
    h16* vtb     = us; us += 2 * apl;   // self-attn V^T hi/lo
    h16* wqb  = us; us += 2 * w1;
    h16* wkvb = us; us += 2 * w2;
    h16* wob  = us; us += 2 * w1;
    h16* fkb  = us; us += 2 * w3;
    h16* fvb  = us; us += 2 * w4;
    h16* rqb  = us; us += 2 * w1;
    h16* rkvb = us; us += 2 * w2;
    h16* rob  = us; us += 2 * w1;

    auto cvtw = [&](const float* src, int Ms, int Ks, int Kp, int Mpad,
                    h16* dst, long pl) {
        const int tot = Mpad * Kp;
        cvt_hilo<<<(tot + 255) / 256, 256, 0, stream>>>(src, Ms, Ks, Kp, dst, pl, tot);
    };
    cvtw(attn_wq,     512,  512,  512, 512,  wqb,  w1);
    cvtw(attn_wkv,    1024, 512,  512, 1024, wkvb, w2);
    cvtw(attn_wo,     512,  512,  512, 512,  wob,  w1);
    cvtw(ff_keys_w,   DFF2, 512,  512, NFF,  fkb,  w3);
    cvtw(ff_values_w, 512,  DFF,  KFF, 512,  fvb,  w4);
    cvtw(res_wq,      512,  512,  512, 512,  rqb,  w1);
    cvtw(res_wkv,    1024,  512,  512, 1024, rkvb, w2);
    cvtw(res_wo,      512,  512,  512, 512,  rob,  w1);

    replicate_kernel<<<(NT * Dm + 255) / 256, 256, 0, stream>>>(
        tok_in, tokens, tokbf, apl, msgs_bf, mpl);

    auto mk = [](const h16* A, long Apl, int lda,
                 const h16* W, long Wpl, int ldw,
                 const float* bias, float* C, int ldc, int Nd,
                 h16* Cbf, long bfpl, int mbase, int K,
                 int mode, int nbx) -> GDesc {
        GDesc d;
        d.A = A; d.Apl = Apl; d.lda = lda;
        d.W = W; d.Wpl = Wpl; d.ldw = ldw;
        d.bias = bias; d.C = C; d.ldc = ldc; d.Nd = Nd;
        d.Cbf = Cbf; d.bfpl = bfpl; d.mbase = mbase; d.K = K;
        d.mode = mode; d.nbx = nbx;
        return d;
    };

    for (int e = 0; e < 3; ++e) {
        rmsnorm3_bf<<<NT, 256, 0, stream>>>(tokens, attn_norm_w, ff_norm_w, res_norm_w,
                                            xa, xf, xr, apl);
        // ---- B1: wq (fp16 out) + wkv (K/V^T fp16 out) + ffk (816 blocks) ----
        {
            GDesc dwq  = mk(xa,    apl, 512, wqb,  w1, 512, nullptr,   nullptr, 512, 512,
                            qhl, apl, 0, 512, 1, 24);
            GDesc dwkv = mk(tokbf, apl, 512, wkvb, w2, 512, nullptr,   (float*)vtb, 1024, 1024,
                            khl, apl, 0, 512, 4, 24);
            GDesc dffk = mk(xf,    apl, 512, fkb,  w3, 512, ff_keys_b, hbuf,  NFF,  DFF2,
                            nullptr, 0, 0, 512, 0, 24);
            mega_gemm<128><<<816, 256, 0, stream>>>(dwq, dwkv, dffk, 96, 288);
        }
        attn_self_mfma<<<BBAT * NH * 4, 256, 0, stream>>>(qhl, khl, vtb, apl, abf);
        glu_gelu_bf<<<NT, 256, 0, stream>>>(hbuf, hbf, hpl);
        // ---- B2: wo + ffv (384 blocks, BM=64) ----
        {
            GDesc dwo  = mk(abf, apl, 512,  wob, w1, 512,  nullptr,     nullptr, 512, 512,
                            msgs_bf + (1 + 2 * e) * (long)NT * Dm, mpl, 0, 512, 1, 48);
            GDesc dffv = mk(hbf, hpl, KFF,  fvb, w4, KFF,  ff_values_b, nullptr, 512, 512,
                            msgs_bf + (2 + 2 * e) * (long)NT * Dm, mpl, 0, KFF, 1, 48);
            mega_gemm<64><<<384, 256, 0, stream>>>(dwo, dffv, dffv, 192, 384);
        }
        // ---- B3: rkv (remap) + rq ----
        {
            const int s0 = (e == 0) ? 0 : (1 + 2 * e);
            const int ns = (e == 0) ? 3 : 2;
            GDesc drkv = mk(msgs_bf + (long)s0 * NT * Dm, mpl, 512, rkvb, w2, 512,
                            nullptr, kvc2, 1024, 1024, nullptr, 0, s0 * 6, 512, 3, ns * 24);
            GDesc drq  = mk(xr, apl, 512, rqb, w1, 512, nullptr, qbuf, 512, 512,
                            nullptr, 0, 0, 512, 0, 24);
            const int nrkv = ns * 24 * 8;
            mega_gemm<128><<<nrkv + 96, 256, 0, stream>>>(drkv, drq, drq, nrkv, nrkv + 96);
        }
        // ---- pooled attention ----
        if (e == 0)      attn_pool_kernel<18><<<512 * NH, 384, 0, stream>>>(qbuf, kvc2, abf, apl);
        else if (e == 1) attn_pool_kernel<30><<<512 * NH, 384, 0, stream>>>(qbuf, kvc2, abf, apl);
        else             attn_pool_kernel<42><<<512 * NH, 384, 0, stream>>>(qbuf, kvc2, abf, apl);
        // ---- B4: ro ----
        {
            if (e < 2) {
                GDesc dro = mk(abf, apl, 512, rob, w1, 512, nullptr, tokens, 512, 512,
                               tokbf, apl, 0, 512, 2, 48);
                mega_gemm<64><<<192, 256, 0, stream>>>(dro, dro, dro, 192, 192);
            } else {
                GDesc dro = mk(abf, apl, 512, rob, w1, 512, nullptr, (float*)d_out, 512, 512,
                               nullptr, 0, 0, 512, 0, 48);
                mega_gemm<64><<<192, 256, 0, stream>>>(dro, dro, dro, 192, 192);
            }
        }
    }
}

// Round 10
// 522.415 us; speedup vs baseline: 1.9196x; 1.9196x over previous
//
#include <hip/hip_runtime.h>
#include <math.h>

// ---- problem constants ----
#define Dm   512
#define Nn_  256
#define Bv   2
#define NTD  1024          // dedup rows: (group g, batch bb, pos nn)
#define NH   8
#define DH   64
#define DFF  1365
#define DFF2 2730
#define KFF  1408
#define NFF  2816
#define NMD  14            // max distinct pooled-context entries (7 sets x 2 groups)
#define EPSR 1.1920929e-07f

// Dedup row r in [0,1024): g=r>>9, bb=(r>>8)&1, nn=r&255.
// Full row (blk,bb,nn) maps to dedup (g=blk/3, bb, nn).  [verified induction:
// pooled ctx batch bq=(2blk+bb)//6 == g, so groups {0,1,2},{3,4,5} stay identical]

typedef _Float16 h16;
typedef h16  v8h  __attribute__((ext_vector_type(8)));
typedef float v4f __attribute__((ext_vector_type(4)));

__device__ inline h16 f2h(float v) { return (h16)v; }

__device__ inline void glds16(const void* g, void* l) {
    __builtin_amdgcn_global_load_lds((const __attribute__((address_space(1))) void*)g,
                                     (__attribute__((address_space(3))) void*)l, 16, 0, 0);
}

// =====================================================================
// Multi-GEMM dispatcher, fp16 3-term compensated, double-buffered LDS
// (round-8 structure: one barrier per 32-k step, stage issued post-barrier).
// modes: 0 fp32 C; 1 fp16 hi/lo Cbf; 2 both; 3 pooled-ctx remap (kvc3);
//        4 attn KV split (K rows / V^T); 5 final output 3-copy expand.
// =====================================================================
struct GDesc {
    const h16* A;
    const h16* W;
    const float* bias;
    float* C;
    h16* Cbf;
    long Apl, Wpl, bfpl;
    int lda, ldw, ldc, Nd, mbase, K, mode, nbx;
};

template <int BM>
__global__ __launch_bounds__(256) void mega_gemm(GDesc d0, GDesc d1, GDesc d2,
                                                 int n0, int n01)
{
    constexpr int MI = BM / 32;
    constexpr int ASEG = BM / 16;
    constexpr int NSEG = 2 * ASEG + 16;
    constexpr int BUF = 2 * BM * 32 + 2 * 4096;
    constexpr int AH = 0, AL = BM * 32, WH = 2 * BM * 32, WL = 2 * BM * 32 + 4096;
    __shared__ h16 lds[2 * BUF];

    GDesc d; int lb = blockIdx.x;
    if (lb < n0) d = d0;
    else if (lb < n01) { d = d1; lb -= n0; }
    else { d = d2; lb -= n01; }
    const int bx = lb % d.nbx;
    const int by = lb / d.nbx;

    const int tid = threadIdx.x;
    const int wid = tid >> 6;
    const int lane = tid & 63;
    const int wm = wid >> 1, wn = wid & 1;
    const int row16 = lane & 15, quad = lane >> 4;
    const long i0 = (long)bx * BM;
    const long j0 = (long)by * 128;
    const int l4 = lane >> 2;
    const int l2s = ((lane & 3) ^ (l4 & 3)) * 8;
    const int ksw = (quad ^ (row16 & 3)) * 8;

    auto stage = [&](int k0, h16* buf) {
        #pragma unroll
        for (int s = 0; s < NSEG / 4; ++s) {
            const int sg = wid * (NSEG / 4) + s;
            const h16* src;
            int dst;
            if (sg < ASEG) {
                src = d.A + (i0 + sg * 16 + l4) * (long)d.lda + k0 + l2s;
                dst = AH + sg * 512;
            } else if (sg < 2 * ASEG) {
                const int r = sg - ASEG;
                src = d.A + d.Apl + (i0 + r * 16 + l4) * (long)d.lda + k0 + l2s;
                dst = AL + r * 512;
            } else if (sg < 2 * ASEG + 8) {
                const int r = sg - 2 * ASEG;
                src = d.W + (j0 + r * 16 + l4) * (long)d.ldw + k0 + l2s;
                dst = WH + r * 512;
            } else {
                const int r = sg - 2 * ASEG - 8;
                src = d.W + d.Wpl + (j0 + r * 16 + l4) * (long)d.ldw + k0 + l2s;
                dst = WL + r * 512;
            }
            glds16(src, &buf[dst]);
        }
    };

    v4f acc[MI][4];
    #pragma unroll
    for (int a = 0; a < MI; ++a)
        #pragma unroll
        for (int b = 0; b < 4; ++b) acc[a][b] = (v4f){0.f, 0.f, 0.f, 0.f};

    stage(0, lds);
    int cur = 0;
    for (int k0 = 0; k0 < d.K; k0 += 32) {
        __syncthreads();
        h16* cbuf = &lds[cur * BUF];
        if (k0 + 32 < d.K) stage(k0 + 32, &lds[(cur ^ 1) * BUF]);

        v8h af[MI], al[MI];
        #pragma unroll
        for (int mi = 0; mi < MI; ++mi) {
            const int aoff = (wm * (BM / 2) + mi * 16 + row16) * 32 + ksw;
            af[mi] = *(const v8h*)&cbuf[AH + aoff];
            al[mi] = *(const v8h*)&cbuf[AL + aoff];
        }
        #pragma unroll
        for (int nj = 0; nj < 4; ++nj) {
            const int boff = (wn * 64 + nj * 16 + row16) * 32 + ksw;
            v8h bh = *(const v8h*)&cbuf[WH + boff];
            v8h bl = *(const v8h*)&cbuf[WL + boff];
            #pragma unroll
            for (int mi = 0; mi < MI; ++mi) {
                acc[mi][nj] = __builtin_amdgcn_mfma_f32_16x16x32_f16(af[mi], bh, acc[mi][nj], 0, 0, 0);
                acc[mi][nj] = __builtin_amdgcn_mfma_f32_16x16x32_f16(af[mi], bl, acc[mi][nj], 0, 0, 0);
                acc[mi][nj] = __builtin_amdgcn_mfma_f32_16x16x32_f16(al[mi], bh, acc[mi][nj], 0, 0, 0);
            }
        }
        cur ^= 1;
    }

    #pragma unroll
    for (int nj = 0; nj < 4; ++nj) {
        const int col = (int)j0 + wn * 64 + nj * 16 + row16;
        if (col < d.Nd) {
            const float bv = d.bias ? d.bias[col] : 0.f;
            #pragma unroll
            for (int mi = 0; mi < MI; ++mi) {
                #pragma unroll
                for (int r = 0; r < 4; ++r) {
                    const long row = i0 + wm * (BM / 2) + mi * 16 + quad * 4 + r;
                    const float v = acc[mi][nj][r] + bv;
                    if (d.mode == 0) {
                        d.C[row * (long)d.ldc + col] = v;
                    } else if (d.mode == 1) {
                        const long idx = row * (long)d.ldc + col;
                        const h16 hi = f2h(v);
                        d.Cbf[idx] = hi; d.Cbf[idx + d.bfpl] = f2h(v - (float)hi);
                    } else if (d.mode == 2) {
                        const long idx = row * (long)d.ldc + col;
                        d.C[idx] = v;
                        const h16 hi = f2h(v);
                        d.Cbf[idx] = hi; d.Cbf[idx + d.bfpl] = f2h(v - (float)hi);
                    } else if (d.mode == 3) {
                        // pooled-ctx remap: r = srel*1024 + (gm,bbm,nn)
                        const int srel = (int)(row >> 10);
                        const int rr = (int)row & 1023;
                        const int md = (d.mbase + srel) * 2 + (rr >> 9);
                        const long orow = (long)(((rr >> 8) & 1) * 256 + (rr & 255)) * NMD + md;
                        d.C[orow * 1024 + col] = v;
                    } else if (d.mode == 4) {
                        const h16 hi = f2h(v);
                        const h16 lo = f2h(v - (float)hi);
                        if (col < 512) {
                            const long idx = row * 512 + col;
                            d.Cbf[idx] = hi; d.Cbf[idx + d.bfpl] = lo;
                        } else {
                            const int c = col - 512;
                            const int bh_ = ((int)(row >> 8)) * 8 + (c >> 6);
                            const long idx = (((long)bh_ * 64 + (c & 63)) << 8) + (row & 255);
                            h16* vtp = (h16*)d.C;
                            vtp[idx] = hi; vtp[idx + d.bfpl] = lo;
                        }
                    } else {
                        // mode 5: expand dedup row to 3 block copies (final out)
                        const int g = (int)(row >> 9), bb = ((int)row >> 8) & 1, nn = (int)row & 255;
                        #pragma unroll
                        for (int rep = 0; rep < 3; ++rep) {
                            const long orow = (long)(((g * 3 + rep) * 2 + bb) * 256 + nn);
                            d.C[orow * (long)d.ldc + col] = v;
                        }
                    }
                }
            }
        }
    }
}

// =====================================================================
__global__ void cvt_hilo(const float* __restrict__ x, int Ms, int Ks, int Kp,
                         h16* __restrict__ y, long plane, int total)
{
    const int idx = blockIdx.x * 256 + threadIdx.x;
    if (idx >= total) return;
    const int row = idx / Kp;
    const int col = idx - row * Kp;
    const float v = (row < Ms && col < Ks) ? x[(long)row * Ks + col] : 0.f;
    const h16 hi = f2h(v);
    y[idx] = hi;
    y[idx + plane] = f2h(v - (float)hi);
}

// =====================================================================
// Triple RMSNorm on dedup rows.
// =====================================================================
__global__ __launch_bounds__(256) void rmsnorm3_bf(
    const float* __restrict__ x,
    const float* __restrict__ w0, const float* __restrict__ w1,
    const float* __restrict__ w2,
    h16* __restrict__ y0, h16* __restrict__ y1,
    h16* __restrict__ y2, long plane)
{
    const int r = blockIdx.x;
    const float* xr = x + (long)r * Dm;
    const int t = threadIdx.x;
    const float a = xr[t];
    const float b = xr[t + 256];
    float ss = a * a + b * b;
    #pragma unroll
    for (int off = 32; off > 0; off >>= 1) ss += __shfl_xor(ss, off, 64);
    __shared__ float w4[4];
    if ((t & 63) == 0) w4[t >> 6] = ss;
    __syncthreads();
    const float rs = rsqrtf((w4[0] + w4[1] + w4[2] + w4[3]) * (1.f / 512.f) + EPSR);
    const float na = a * rs, nb = b * rs;
    const long ia = (long)r * Dm + t, ib = ia + 256;
    h16 h;
    float v;
    v = na * w0[t];       h = f2h(v); y0[ia] = h; y0[ia + plane] = f2h(v - (float)h);
    v = nb * w0[t + 256]; h = f2h(v); y0[ib] = h; y0[ib + plane] = f2h(v - (float)h);
    v = na * w1[t];       h = f2h(v); y1[ia] = h; y1[ia + plane] = f2h(v - (float)h);
    v = nb * w1[t + 256]; h = f2h(v); y1[ib] = h; y1[ib + plane] = f2h(v - (float)h);
    v = na * w2[t];       h = f2h(v); y2[ia] = h; y2[ia + plane] = f2h(v - (float)h);
    v = nb * w2[t + 256]; h = f2h(v); y2[ib] = h; y2[ib + plane] = f2h(v - (float)h);
}

// =====================================================================
__global__ __launch_bounds__(256) void glu_gelu_bf(
    const float* __restrict__ h, h16* __restrict__ y, long plane)
{
    const int r = blockIdx.x;
    const float* row = h + (long)r * NFF;
    for (int c = threadIdx.x; c < KFF; c += 256) {
        float v = 0.f;
        if (c < DFF) {
            const float sim = row[c];
            const float g = row[c + DFF];
            v = sim * (0.5f * g * (1.f + erff(g * 0.70710678118654752440f)));
        }
        const long idx = (long)r * KFF + c;
        const h16 hi = f2h(v);
        y[idx] = hi;
        y[idx + plane] = f2h(v - (float)hi);
    }
}

// =====================================================================
// MFMA flash self-attention on dedup batches. Grid = bat(4) x head(8)
// x qtile(4) = 128 blocks; 256 thr.
// =====================================================================
__global__ __launch_bounds__(256) void attn_self_mfma(
    const h16* __restrict__ qhl, const h16* __restrict__ khl,
    const h16* __restrict__ vtb, long pl, h16* __restrict__ outbf)
{
    __shared__ h16 kh[4096], kl[4096], vh[4096], vl[4096];
    __shared__ h16 pH[4 * 1024], pL[4 * 1024];

    const int bat = blockIdx.x >> 5;
    const int head = (blockIdx.x >> 2) & 7;
    const int qc = blockIdx.x & 3;
    const int t = threadIdx.x;
    const int w = t >> 6, lane = t & 63;
    const int row16 = lane & 15, quad = lane >> 4;

    v8h qh[2], ql[2];
    {
        const long qrow = (long)bat * 256 + qc * 64 + w * 16 + row16;
        const h16* qp = qhl + qrow * 512 + head * 64 + quad * 8;
        qh[0] = *(const v8h*)qp;        qh[1] = *(const v8h*)(qp + 32);
        ql[0] = *(const v8h*)(qp + pl); ql[1] = *(const v8h*)(qp + pl + 32);
    }

    v4f O[4];
    #pragma unroll
    for (int i = 0; i < 4; ++i) O[i] = (v4f){0.f, 0.f, 0.f, 0.f};
    float m[4] = {-1e30f, -1e30f, -1e30f, -1e30f};
    float l[4] = {0.f, 0.f, 0.f, 0.f};

    const int sj = t >> 3;
    const int sc = t & 7;
    const long kbase = ((long)bat * 256) * 512 + head * 64;
    const long vbase = ((long)(bat * 8 + head) * 64) << 8;

    for (int jc = 0; jc < 256; jc += 64) {
        __syncthreads();
        #pragma unroll
        for (int rep = 0; rep < 2; ++rep) {
            const int row = sj + rep * 32;
            const int dsw = row * 64 + ((sc ^ (row & 7)) * 8);
            const h16* ks = khl + kbase + (long)(jc + row) * 512 + sc * 8;
            const h16* vs = vtb + vbase + ((long)row << 8) + jc + sc * 8;
            *(v8h*)&kh[dsw] = *(const v8h*)ks;
            *(v8h*)&kl[dsw] = *(const v8h*)(ks + pl);
            *(v8h*)&vh[dsw] = *(const v8h*)vs;
            *(v8h*)&vl[dsw] = *(const v8h*)(vs + pl);
        }
        __syncthreads();

        v4f S[4];
        #pragma unroll
        for (int i = 0; i < 4; ++i) S[i] = (v4f){0.f, 0.f, 0.f, 0.f};
        #pragma unroll
        for (int kk = 0; kk < 2; ++kk) {
            #pragma unroll
            for (int tile = 0; tile < 4; ++tile) {
                const int off = (tile * 16 + row16) * 64 + (((kk * 4 + quad) ^ (row16 & 7)) * 8);
                v8h bh = *(const v8h*)&kh[off];
                v8h bl = *(const v8h*)&kl[off];
                S[tile] = __builtin_amdgcn_mfma_f32_16x16x32_f16(qh[kk], bh, S[tile], 0, 0, 0);
                S[tile] = __builtin_amdgcn_mfma_f32_16x16x32_f16(qh[kk], bl, S[tile], 0, 0, 0);
                S[tile] = __builtin_amdgcn_mfma_f32_16x16x32_f16(ql[kk], bh, S[tile], 0, 0, 0);
            }
        }

        float mc[4], sums[4], alpha[4];
        #pragma unroll
        for (int r = 0; r < 4; ++r) {
            float v = fmaxf(fmaxf(S[0][r], S[1][r]), fmaxf(S[2][r], S[3][r]));
            v = fmaxf(v, __shfl_xor(v, 1, 64));
            v = fmaxf(v, __shfl_xor(v, 2, 64));
            v = fmaxf(v, __shfl_xor(v, 4, 64));
            v = fmaxf(v, __shfl_xor(v, 8, 64));
            mc[r] = v;
        }
        #pragma unroll
        for (int r = 0; r < 4; ++r) {
            const float mn = fmaxf(m[r], mc[r]);
            alpha[r] = __expf(m[r] - mn);
            m[r] = mn;
            sums[r] = 0.f;
        }
        #pragma unroll
        for (int tile = 0; tile < 4; ++tile) {
            #pragma unroll
            for (int r = 0; r < 4; ++r) {
                const float p = __expf(S[tile][r] - m[r]);
                S[tile][r] = p;
                sums[r] += p;
            }
        }
        #pragma unroll
        for (int r = 0; r < 4; ++r) {
            float v = sums[r];
            v += __shfl_xor(v, 1, 64);
            v += __shfl_xor(v, 2, 64);
            v += __shfl_xor(v, 4, 64);
            v += __shfl_xor(v, 8, 64);
            l[r] = l[r] * alpha[r] + v;
        }
        #pragma unroll
        for (int tile = 0; tile < 4; ++tile)
            #pragma unroll
            for (int r = 0; r < 4; ++r) O[tile][r] *= alpha[r];

        #pragma unroll
        for (int tile = 0; tile < 4; ++tile) {
            const int chunkcol = tile * 2 + (row16 >> 3);
            #pragma unroll
            for (int r = 0; r < 4; ++r) {
                const int prow = quad * 4 + r;
                const int addr = w * 1024 + prow * 64 +
                                 ((chunkcol ^ (prow & 7)) * 8) + (row16 & 7);
                const float p = S[tile][r];
                const h16 hi = f2h(p);
                pH[addr] = hi;
                pL[addr] = f2h(p - (float)hi);
            }
        }

        #pragma unroll
        for (int kk = 0; kk < 2; ++kk) {
            const int poff = w * 1024 + row16 * 64 + (((kk * 4 + quad) ^ (row16 & 7)) * 8);
            v8h pa = *(const v8h*)&pH[poff];
            v8h pb = *(const v8h*)&pL[poff];
            #pragma unroll
            for (int tile = 0; tile < 4; ++tile) {
                const int off = (tile * 16 + row16) * 64 + (((kk * 4 + quad) ^ (row16 & 7)) * 8);
                v8h vbh = *(const v8h*)&vh[off];
                v8h vbl = *(const v8h*)&vl[off];
                O[tile] = __builtin_amdgcn_mfma_f32_16x16x32_f16(pa, vbh, O[tile], 0, 0, 0);
                O[tile] = __builtin_amdgcn_mfma_f32_16x16x32_f16(pa, vbl, O[tile], 0, 0, 0);
                O[tile] = __builtin_amdgcn_mfma_f32_16x16x32_f16(pb, vbh, O[tile], 0, 0, 0);
            }
        }
    }

    #pragma unroll
    for (int tile = 0; tile < 4; ++tile) {
        const int dim = tile * 16 + row16;
        #pragma unroll
        for (int r = 0; r < 4; ++r) {
            const long grow = (long)bat * 256 + qc * 64 + w * 16 + quad * 4 + r;
            const float v = O[tile][r] / l[r];
            const long idx = grow * 512 + head * 64 + dim;
            const h16 hi = f2h(v);
            outbf[idx] = hi;
            outbf[idx + pl] = f2h(v - (float)hi);
        }
    }
}

// =====================================================================
// Pooled attention over DISTINCT ctx entries (uniform multiplicity 3
// cancels in softmax). Block per (rb = g*256+nn, head); 128 thr = 2
// waves (one per bb). kvc3 row layout: [rb*NMD + md][1024].
// =====================================================================
template <int M>
__global__ __launch_bounds__(128) void attn_pool_kernel(
    const float* __restrict__ qb, const float* __restrict__ kvc3,
    h16* __restrict__ outbf, long plane)
{
    const int rb = blockIdx.x >> 3;
    const int h = blockIdx.x & 7;
    __shared__ float k_lds[M * 66];
    __shared__ float v_lds[M * 66];
    __shared__ float q_lds[2 * 64];
    __shared__ float p_lds[2 * 64];
    const int t = threadIdx.x;
    const int g = rb >> 8, nn = rb & 255;

    for (int idx = t; idx < M * 64; idx += 128) {
        const int m = idx >> 6, d = idx & 63;
        const long base = ((long)rb * NMD + m) * 1024 + h * DH + d;
        k_lds[m * 66 + d] = kvc3[base];
        v_lds[m * 66 + d] = kvc3[base + 512];
    }
    {
        const int w = t >> 6, dd = t & 63;
        const long iq = (long)(g * 2 + w) * 256 + nn;
        q_lds[t] = qb[iq * Dm + h * DH + dd];
    }
    __syncthreads();

    const int w = t >> 6;          // bb
    const int lane = t & 63;
    float s = -1e30f;
    if (lane < M) {
        s = 0.f;
        const float* kr = &k_lds[lane * 66];
        const float* qr = &q_lds[w * 64];
        #pragma unroll
        for (int dd = 0; dd < 64; dd += 2) {
            s = fmaf(qr[dd], kr[dd], s);
            s = fmaf(qr[dd + 1], kr[dd + 1], s);
        }
    }
    float mx = s;
    #pragma unroll
    for (int off = 32; off > 0; off >>= 1) mx = fmaxf(mx, __shfl_xor(mx, off, 64));
    const float p = __expf(s - mx);
    float l = p;
    #pragma unroll
    for (int off = 32; off > 0; off >>= 1) l += __shfl_xor(l, off, 64);
    p_lds[w * 64 + lane] = p / l;

    float o = 0.f;
    const float* pr = &p_lds[w * 64];
    #pragma unroll
    for (int m = 0; m < M; ++m)
        o = fmaf(pr[m], v_lds[m * 66 + lane], o);

    const long iq = (long)(g * 2 + w) * 256 + nn;
    const long oidx = iq * Dm + h * DH + lane;
    const h16 hi = f2h(o);
    outbf[oidx] = hi;
    outbf[oidx + plane] = f2h(o - (float)hi);
}

// =====================================================================
// Broadcast tokens -> dedup tokens fp32 (both groups), tokbf, msgs set0
// =====================================================================
__global__ void replicate_kernel(const float* __restrict__ src,
                                 float* __restrict__ tokens,
                                 h16* __restrict__ tokbf, long tpl,
                                 h16* __restrict__ msg0, long mpl)
{
    const int idx = blockIdx.x * blockDim.x + threadIdx.x;
    if (idx >= NTD * Dm) return;
    const float v = src[idx & (Bv * Nn_ * Dm - 1)];   // 2^18-1: (bb,nn,col)
    tokens[idx] = v;
    const h16 hi = f2h(v);
    const h16 lo = f2h(v - (float)hi);
    tokbf[idx] = hi; tokbf[idx + tpl] = lo;
    msg0[idx] = hi; msg0[idx + mpl] = lo;
}

// =====================================================================
extern "C" void kernel_launch(void* const* d_in, const int* in_sizes, int n_in,
                              void* d_out, int out_size, void* d_ws, size_t ws_size,
                              hipStream_t stream)
{
    const float* tok_in       = (const float*)d_in[0];
    const float* attn_norm_w  = (const float*)d_in[1];
    const float* attn_wq      = (const float*)d_in[2];
    const float* attn_wkv     = (const float*)d_in[3];
    const float* attn_wo      = (const float*)d_in[4];
    const float* ff_norm_w    = (const float*)d_in[5];
    const float* ff_keys_w    = (const float*)d_in[6];
    const float* ff_keys_b    = (const float*)d_in[7];
    const float* ff_values_w  = (const float*)d_in[8];
    const float* ff_values_b  = (const float*)d_in[9];
    const float* res_norm_w   = (const float*)d_in[10];
    const float* res_wq       = (const float*)d_in[11];
    const float* res_wkv      = (const float*)d_in[12];
    const float* res_wo       = (const float*)d_in[13];

    float* ws = (float*)d_ws;
    float* kvc3   = ws;                                  // 512*14*1024
    float* tokens = kvc3 + 512L * NMD * 1024;            // NTD*512
    float* qbuf   = tokens + (long)NTD * Dm;             // NTD*512 (pool q)
    float* hbuf   = qbuf + (long)NTD * Dm;               // NTD*2816

    h16* us = (h16*)(hbuf + (long)NTD * NFF);
    const long apl = (long)NTD * Dm;         // activation plane (dedup)
    const long mpl = 7L * NTD * Dm;          // msgs plane (7 sets)
    const long hpl = (long)NTD * KFF;
    const long vtpl = (long)NTD * Dm;        // 4*8*64*256 == NTD*512
    const long w1 = 512L * 512, w2 = 1024L * 512, w3 = (long)NFF * 512, w4 = 512L * KFF;
    h16* msgs_bf = us; us += 2 * mpl;
    h16* tokbf   = us; us += 2 * apl;
    h16* xa      = us; us += 2 * apl;
    h16* xf      = us; us += 2 * apl;
    h16* xr      = us; us += 2 * apl;
    h16* abf     = us; us += 2 * apl;
    h16* hbf     = us; us += 2 * hpl;
    h16* qhl     = us; us += 2 * apl;
    h16* khl     = us; us += 2 * apl;
    h16* vtb     = us; us += 2 * vtpl;
    h16* wqb  = us; us += 2 * w1;
    h16* wkvb = us; us += 2 * w2;
    h16* wob  = us; us += 2 * w1;
    h16* fkb  = us; us += 2 * w3;
    h16* fvb  = us; us += 2 * w4;
    h16* rqb  = us; us += 2 * w1;
    h16* rkvb = us; us += 2 * w2;
    h16* rob  = us; us += 2 * w1;

    auto cvtw = [&](const float* src, int Ms, int Ks, int Kp, int Mpad,
                    h16* dst, long pl) {
        const int tot = Mpad * Kp;
        cvt_hilo<<<(tot + 255) / 256, 256, 0, stream>>>(src, Ms, Ks, Kp, dst, pl, tot);
    };
    cvtw(attn_wq,     512,  512,  512, 512,  wqb,  w1);
    cvtw(attn_wkv,    1024, 512,  512, 1024, wkvb, w2);
    cvtw(attn_wo,     512,  512,  512, 512,  wob,  w1);
    cvtw(ff_keys_w,   DFF2, 512,  512, NFF,  fkb,  w3);
    cvtw(ff_values_w, 512,  DFF,  KFF, 512,  fvb,  w4);
    cvtw(res_wq,      512,  512,  512, 512,  rqb,  w1);
    cvtw(res_wkv,    1024,  512,  512, 1024, rkvb, w2);
    cvtw(res_wo,      512,  512,  512, 512,  rob,  w1);

    replicate_kernel<<<(NTD * Dm + 255) / 256, 256, 0, stream>>>(
        tok_in, tokens, tokbf, apl, msgs_bf, mpl);

    auto mk = [](const h16* A, long Apl, int lda,
                 const h16* W, long Wpl, int ldw,
                 const float* bias, float* C, int ldc, int Nd,
                 h16* Cbf, long bfpl, int mbase, int K,
                 int mode, int nbx) -> GDesc {
        GDesc d;
        d.A = A; d.Apl = Apl; d.lda = lda;
        d.W = W; d.Wpl = Wpl; d.ldw = ldw;
        d.bias = bias; d.C = C; d.ldc = ldc; d.Nd = Nd;
        d.Cbf = Cbf; d.bfpl = bfpl; d.mbase = mbase; d.K = K;
        d.mode = mode; d.nbx = nbx;
        return d;
    };

    for (int e = 0; e < 3; ++e) {
        rmsnorm3_bf<<<NTD, 256, 0, stream>>>(tokens, attn_norm_w, ff_norm_w, res_norm_w,
                                             xa, xf, xr, apl);
        // ---- B1: wq + wkv(K/V^T) + ffk (64+128+352 = 544 blocks, BM=64) ----
        {
            GDesc dwq  = mk(xa,    apl, 512, wqb,  w1, 512, nullptr,   nullptr, 512, 512,
                            qhl, apl, 0, 512, 1, 16);
            GDesc dwkv = mk(tokbf, apl, 512, wkvb, w2, 512, nullptr,   (float*)vtb, 1024, 1024,
                            khl, apl, 0, 512, 4, 16);
            GDesc dffk = mk(xf,    apl, 512, fkb,  w3, 512, ff_keys_b, hbuf,  NFF,  DFF2,
                            nullptr, 0, 0, 512, 0, 16);
            mega_gemm<64><<<544, 256, 0, stream>>>(dwq, dwkv, dffk, 64, 192);
        }
        attn_self_mfma<<<4 * NH * 4, 256, 0, stream>>>(qhl, khl, vtb, apl, abf);
        glu_gelu_bf<<<NTD, 256, 0, stream>>>(hbuf, hbf, hpl);
        // ---- B2: wo + ffv + rq (64+64+64 = 192 blocks) ----
        {
            GDesc dwo  = mk(abf, apl, 512,  wob, w1, 512,  nullptr,     nullptr, 512, 512,
                            msgs_bf + (1 + 2 * e) * (long)NTD * Dm, mpl, 0, 512, 1, 16);
            GDesc dffv = mk(hbf, hpl, KFF,  fvb, w4, KFF,  ff_values_b, nullptr, 512, 512,
                            msgs_bf + (2 + 2 * e) * (long)NTD * Dm, mpl, 0, KFF, 1, 16);
            GDesc drq  = mk(xr, apl, 512, rqb, w1, 512, nullptr, qbuf, 512, 512,
                            nullptr, 0, 0, 512, 0, 16);
            mega_gemm<64><<<192, 256, 0, stream>>>(dwo, dffv, drq, 64, 128);
        }
        // ---- B3: rkv (remap to kvc3) ----
        {
            const int s0 = (e == 0) ? 0 : (1 + 2 * e);
            const int ns = (e == 0) ? 3 : 2;
            GDesc drkv = mk(msgs_bf + (long)s0 * NTD * Dm, mpl, 512, rkvb, w2, 512,
                            nullptr, kvc3, 1024, 1024, nullptr, 0, s0, 512, 3, ns * 16);
            const int nb = ns * 16 * 8;
            mega_gemm<64><<<nb, 256, 0, stream>>>(drkv, drkv, drkv, nb, nb);
        }
        // ---- pooled attention (distinct entries) ----
        if (e == 0)      attn_pool_kernel<6><<<512 * NH, 128, 0, stream>>>(qbuf, kvc3, abf, apl);
        else if (e == 1) attn_pool_kernel<10><<<512 * NH, 128, 0, stream>>>(qbuf, kvc3, abf, apl);
        else             attn_pool_kernel<14><<<512 * NH, 128, 0, stream>>>(qbuf, kvc3, abf, apl);
        // ---- B4: ro ----
        {
            if (e < 2) {
                GDesc dro = mk(abf, apl, 512, rob, w1, 512, nullptr, tokens, 512, 512,
                               tokbf, apl, 0, 512, 2, 16);
                mega_gemm<64><<<64, 256, 0, stream>>>(dro, dro, dro, 64, 64);
            } else {
                GDesc dro = mk(abf, apl, 512, rob, w1, 512, nullptr, (float*)d_out, 512, 512,
                               nullptr, 0, 0, 512, 5, 16);
                mega_gemm<64><<<64, 256, 0, stream>>>(dro, dro, dro, 64, 64);
            }
        }
    }
}

// Round 11
// 490.413 us; speedup vs baseline: 2.0449x; 1.0653x over previous
//
#include <hip/hip_runtime.h>
#include <math.h>

// ---- problem constants ----
#define Dm   512
#define Nn_  256
#define Bv   2
#define NTD  1024          // dedup rows: (group g, batch bb, pos nn)
#define NH   8
#define DH   64
#define DFF  1365
#define DFF2 2730
#define KFF  1408
#define NFF  2816
#define NMD  14            // max distinct pooled-context entries (7 sets x 2 groups)
#define EPSR 1.1920929e-07f

typedef _Float16 h16;
typedef h16  v8h  __attribute__((ext_vector_type(8)));
typedef float v4f __attribute__((ext_vector_type(4)));

__device__ inline h16 f2h(float v) { return (h16)v; }

__device__ inline void glds16(const void* g, void* l) {
    __builtin_amdgcn_global_load_lds((const __attribute__((address_space(1))) void*)g,
                                     (__attribute__((address_space(3))) void*)l, 16, 0, 0);
}

// =====================================================================
// Multi-GEMM dispatcher (4 descriptors), fp16 3-term compensated,
// double-buffered LDS. modes: 0 fp32 C; 1 fp16 hi/lo Cbf; 2 both;
// 3 pooled-ctx remap (kvc3, md = mbase*2 + group); 4 attn KV split;
// 5 final-output 3-copy expand.
// =====================================================================
struct GDesc {
    const h16* A;
    const h16* W;
    const float* bias;
    float* C;
    h16* Cbf;
    long Apl, Wpl, bfpl;
    int lda, ldw, ldc, Nd, mbase, K, mode, nbx;
};

template <int BM>
__global__ __launch_bounds__(256) void mega_gemm(GDesc d0, GDesc d1, GDesc d2, GDesc d3,
                                                 int n0, int n01, int n012)
{
    constexpr int MI = BM / 32;
    constexpr int ASEG = BM / 16;
    constexpr int NSEG = 2 * ASEG + 16;
    constexpr int BUF = 2 * BM * 32 + 2 * 4096;
    constexpr int AH = 0, AL = BM * 32, WH = 2 * BM * 32, WL = 2 * BM * 32 + 4096;
    __shared__ h16 lds[2 * BUF];

    GDesc d; int lb = blockIdx.x;
    if (lb < n0) d = d0;
    else if (lb < n01) { d = d1; lb -= n0; }
    else if (lb < n012) { d = d2; lb -= n01; }
    else { d = d3; lb -= n012; }
    const int bx = lb % d.nbx;
    const int by = lb / d.nbx;

    const int tid = threadIdx.x;
    const int wid = tid >> 6;
    const int lane = tid & 63;
    const int wm = wid >> 1, wn = wid & 1;
    const int row16 = lane & 15, quad = lane >> 4;
    const long i0 = (long)bx * BM;
    const long j0 = (long)by * 128;
    const int l4 = lane >> 2;
    const int l2s = ((lane & 3) ^ (l4 & 3)) * 8;
    const int ksw = (quad ^ (row16 & 3)) * 8;

    auto stage = [&](int k0, h16* buf) {
        #pragma unroll
        for (int s = 0; s < NSEG / 4; ++s) {
            const int sg = wid * (NSEG / 4) + s;
            const h16* src;
            int dst;
            if (sg < ASEG) {
                src = d.A + (i0 + sg * 16 + l4) * (long)d.lda + k0 + l2s;
                dst = AH + sg * 512;
            } else if (sg < 2 * ASEG) {
                const int r = sg - ASEG;
                src = d.A + d.Apl + (i0 + r * 16 + l4) * (long)d.lda + k0 + l2s;
                dst = AL + r * 512;
            } else if (sg < 2 * ASEG + 8) {
                const int r = sg - 2 * ASEG;
                src = d.W + (j0 + r * 16 + l4) * (long)d.ldw + k0 + l2s;
                dst = WH + r * 512;
            } else {
                const int r = sg - 2 * ASEG - 8;
                src = d.W + d.Wpl + (j0 + r * 16 + l4) * (long)d.ldw + k0 + l2s;
                dst = WL + r * 512;
            }
            glds16(src, &buf[dst]);
        }
    };

    v4f acc[MI][4];
    #pragma unroll
    for (int a = 0; a < MI; ++a)
        #pragma unroll
        for (int b = 0; b < 4; ++b) acc[a][b] = (v4f){0.f, 0.f, 0.f, 0.f};

    stage(0, lds);
    int cur = 0;
    for (int k0 = 0; k0 < d.K; k0 += 32) {
        __syncthreads();
        h16* cbuf = &lds[cur * BUF];
        if (k0 + 32 < d.K) stage(k0 + 32, &lds[(cur ^ 1) * BUF]);

        v8h af[MI], al[MI];
        #pragma unroll
        for (int mi = 0; mi < MI; ++mi) {
            const int aoff = (wm * (BM / 2) + mi * 16 + row16) * 32 + ksw;
            af[mi] = *(const v8h*)&cbuf[AH + aoff];
            al[mi] = *(const v8h*)&cbuf[AL + aoff];
        }
        #pragma unroll
        for (int nj = 0; nj < 4; ++nj) {
            const int boff = (wn * 64 + nj * 16 + row16) * 32 + ksw;
            v8h bh = *(const v8h*)&cbuf[WH + boff];
            v8h bl = *(const v8h*)&cbuf[WL + boff];
            #pragma unroll
            for (int mi = 0; mi < MI; ++mi) {
                acc[mi][nj] = __builtin_amdgcn_mfma_f32_16x16x32_f16(af[mi], bh, acc[mi][nj], 0, 0, 0);
                acc[mi][nj] = __builtin_amdgcn_mfma_f32_16x16x32_f16(af[mi], bl, acc[mi][nj], 0, 0, 0);
                acc[mi][nj] = __builtin_amdgcn_mfma_f32_16x16x32_f16(al[mi], bh, acc[mi][nj], 0, 0, 0);
            }
        }
        cur ^= 1;
    }

    #pragma unroll
    for (int nj = 0; nj < 4; ++nj) {
        const int col = (int)j0 + wn * 64 + nj * 16 + row16;
        if (col < d.Nd) {
            const float bv = d.bias ? d.bias[col] : 0.f;
            #pragma unroll
            for (int mi = 0; mi < MI; ++mi) {
                #pragma unroll
                for (int r = 0; r < 4; ++r) {
                    const long row = i0 + wm * (BM / 2) + mi * 16 + quad * 4 + r;
                    const float v = acc[mi][nj][r] + bv;
                    if (d.mode == 0) {
                        d.C[row * (long)d.ldc + col] = v;
                    } else if (d.mode == 1) {
                        const long idx = row * (long)d.ldc + col;
                        const h16 hi = f2h(v);
                        d.Cbf[idx] = hi; d.Cbf[idx + d.bfpl] = f2h(v - (float)hi);
                    } else if (d.mode == 2) {
                        const long idx = row * (long)d.ldc + col;
                        d.C[idx] = v;
                        const h16 hi = f2h(v);
                        d.Cbf[idx] = hi; d.Cbf[idx + d.bfpl] = f2h(v - (float)hi);
                    } else if (d.mode == 3) {
                        // row = (gm, bbm, nn); store at line (bbm,nn), entry mbase*2+gm
                        const int rr = (int)row & 1023;
                        const int md = d.mbase * 2 + (rr >> 9);
                        const long orow = (long)(((rr >> 8) & 1) * 256 + (rr & 255)) * NMD + md;
                        d.C[orow * 1024 + col] = v;
                    } else if (d.mode == 4) {
                        const h16 hi = f2h(v);
                        const h16 lo = f2h(v - (float)hi);
                        if (col < 512) {
                            const long idx = row * 512 + col;
                            d.Cbf[idx] = hi; d.Cbf[idx + d.bfpl] = lo;
                        } else {
                            const int c = col - 512;
                            const int bh_ = ((int)(row >> 8)) * 8 + (c >> 6);
                            const long idx = (((long)bh_ * 64 + (c & 63)) << 8) + (row & 255);
                            h16* vtp = (h16*)d.C;
                            vtp[idx] = hi; vtp[idx + d.bfpl] = lo;
                        }
                    } else {
                        const int g = (int)(row >> 9), bb = ((int)row >> 8) & 1, nn = (int)row & 255;
                        #pragma unroll
                        for (int rep = 0; rep < 3; ++rep) {
                            const long orow = (long)(((g * 3 + rep) * 2 + bb) * 256 + nn);
                            d.C[orow * (long)d.ldc + col] = v;
                        }
                    }
                }
            }
        }
    }
}

// =====================================================================
__global__ void cvt_hilo(const float* __restrict__ x, int Ms, int Ks, int Kp,
                         h16* __restrict__ y, long plane, int total)
{
    const int idx = blockIdx.x * 256 + threadIdx.x;
    if (idx >= total) return;
    const int row = idx / Kp;
    const int col = idx - row * Kp;
    const float v = (row < Ms && col < Ks) ? x[(long)row * Ks + col] : 0.f;
    const h16 hi = f2h(v);
    y[idx] = hi;
    y[idx + plane] = f2h(v - (float)hi);
}

// Transposed convert: src [R, C] fp32 -> dst [Cpad, R] hi/lo (rows >= C zero)
__global__ void cvt_hilo_T(const float* __restrict__ x, int R, int C,
                           h16* __restrict__ y, long plane, int total)
{
    const int idx = blockIdx.x * 256 + threadIdx.x;
    if (idx >= total) return;
    const int row = idx / R;     // src col
    const int col = idx - row * R;  // src row
    const float v = (row < C) ? x[(long)col * C + row] : 0.f;
    const h16 hi = f2h(v);
    y[idx] = hi;
    y[idx + plane] = f2h(v - (float)hi);
}

// biasWf[n] = sum_d res_wkv[n,d] * ff_values_b[d]
__global__ void fold_bias(const float* __restrict__ wkv, const float* __restrict__ b,
                          float* __restrict__ out)
{
    const int n = blockIdx.x * 256 + threadIdx.x;
    if (n >= 1024) return;
    float s = 0.f;
    const float* row = wkv + (long)n * 512;
    for (int d2 = 0; d2 < 512; ++d2) s = fmaf(row[d2], b[d2], s);
    out[n] = s;
}

// =====================================================================
// Triple RMSNorm on dedup rows.
// =====================================================================
__global__ __launch_bounds__(256) void rmsnorm3_bf(
    const float* __restrict__ x,
    const float* __restrict__ w0, const float* __restrict__ w1,
    const float* __restrict__ w2,
    h16* __restrict__ y0, h16* __restrict__ y1,
    h16* __restrict__ y2, long plane)
{
    const int r = blockIdx.x;
    const float* xr = x + (long)r * Dm;
    const int t = threadIdx.x;
    const float a = xr[t];
    const float b = xr[t + 256];
    float ss = a * a + b * b;
    #pragma unroll
    for (int off = 32; off > 0; off >>= 1) ss += __shfl_xor(ss, off, 64);
    __shared__ float w4[4];
    if ((t & 63) == 0) w4[t >> 6] = ss;
    __syncthreads();
    const float rs = rsqrtf((w4[0] + w4[1] + w4[2] + w4[3]) * (1.f / 512.f) + EPSR);
    const float na = a * rs, nb = b * rs;
    const long ia = (long)r * Dm + t, ib = ia + 256;
    h16 h;
    float v;
    v = na * w0[t];       h = f2h(v); y0[ia] = h; y0[ia + plane] = f2h(v - (float)h);
    v = nb * w0[t + 256]; h = f2h(v); y0[ib] = h; y0[ib + plane] = f2h(v - (float)h);
    v = na * w1[t];       h = f2h(v); y1[ia] = h; y1[ia + plane] = f2h(v - (float)h);
    v = nb * w1[t + 256]; h = f2h(v); y1[ib] = h; y1[ib + plane] = f2h(v - (float)h);
    v = na * w2[t];       h = f2h(v); y2[ia] = h; y2[ia + plane] = f2h(v - (float)h);
    v = nb * w2[t + 256]; h = f2h(v); y2[ib] = h; y2[ib + plane] = f2h(v - (float)h);
}

// =====================================================================
// Fused MFMA flash self-attention (blocks 0..127) + GLU-GELU (128..1151).
// =====================================================================
__global__ __launch_bounds__(256) void attn_glu(
    const h16* __restrict__ qhl, const h16* __restrict__ khl,
    const h16* __restrict__ vtb, long pl, h16* __restrict__ outbf,
    const float* __restrict__ hbuf, h16* __restrict__ hbf, long hpl)
{
    if (blockIdx.x >= 128) {
        // ---- GLU * exact GELU ----
        const int r = blockIdx.x - 128;
        const float* row = hbuf + (long)r * NFF;
        for (int c = threadIdx.x; c < KFF; c += 256) {
            float v = 0.f;
            if (c < DFF) {
                const float sim = row[c];
                const float g = row[c + DFF];
                v = sim * (0.5f * g * (1.f + erff(g * 0.70710678118654752440f)));
            }
            const long idx = (long)r * KFF + c;
            const h16 hi = f2h(v);
            hbf[idx] = hi;
            hbf[idx + hpl] = f2h(v - (float)hi);
        }
        return;
    }

    __shared__ h16 kh[4096], kl[4096], vh[4096], vl[4096];
    __shared__ h16 pH[4 * 1024], pL[4 * 1024];

    const int bat = blockIdx.x >> 5;
    const int head = (blockIdx.x >> 2) & 7;
    const int qc = blockIdx.x & 3;
    const int t = threadIdx.x;
    const int w = t >> 6, lane = t & 63;
    const int row16 = lane & 15, quad = lane >> 4;

    v8h qh[2], ql[2];
    {
        const long qrow = (long)bat * 256 + qc * 64 + w * 16 + row16;
        const h16* qp = qhl + qrow * 512 + head * 64 + quad * 8;
        qh[0] = *(const v8h*)qp;        qh[1] = *(const v8h*)(qp + 32);
        ql[0] = *(const v8h*)(qp + pl); ql[1] = *(const v8h*)(qp + pl + 32);
    }

    v4f O[4];
    #pragma unroll
    for (int i = 0; i < 4; ++i) O[i] = (v4f){0.f, 0.f, 0.f, 0.f};
    float m[4] = {-1e30f, -1e30f, -1e30f, -1e30f};
    float l[4] = {0.f, 0.f, 0.f, 0.f};

    const int sj = t >> 3;
    const int sc = t & 7;
    const long kbase = ((long)bat * 256) * 512 + head * 64;
    const long vbase = ((long)(bat * 8 + head) * 64) << 8;

    for (int jc = 0; jc < 256; jc += 64) {
        __syncthreads();
        #pragma unroll
        for (int rep = 0; rep < 2; ++rep) {
            const int row = sj + rep * 32;
            const int dsw = row * 64 + ((sc ^ (row & 7)) * 8);
            const h16* ks = khl + kbase + (long)(jc + row) * 512 + sc * 8;
            const h16* vs = vtb + vbase + ((long)row << 8) + jc + sc * 8;
            *(v8h*)&kh[dsw] = *(const v8h*)ks;
            *(v8h*)&kl[dsw] = *(const v8h*)(ks + pl);
            *(v8h*)&vh[dsw] = *(const v8h*)vs;
            *(v8h*)&vl[dsw] = *(const v8h*)(vs + pl);
        }
        __syncthreads();

        v4f S[4];
        #pragma unroll
        for (int i = 0; i < 4; ++i) S[i] = (v4f){0.f, 0.f, 0.f, 0.f};
        #pragma unroll
        for (int kk = 0; kk < 2; ++kk) {
            #pragma unroll
            for (int tile = 0; tile < 4; ++tile) {
                const int off = (tile * 16 + row16) * 64 + (((kk * 4 + quad) ^ (row16 & 7)) * 8);
                v8h bh = *(const v8h*)&kh[off];
                v8h bl = *(const v8h*)&kl[off];
                S[tile] = __builtin_amdgcn_mfma_f32_16x16x32_f16(qh[kk], bh, S[tile], 0, 0, 0);
                S[tile] = __builtin_amdgcn_mfma_f32_16x16x32_f16(qh[kk], bl, S[tile], 0, 0, 0);
                S[tile] = __builtin_amdgcn_mfma_f32_16x16x32_f16(ql[kk], bh, S[tile], 0, 0, 0);
            }
        }

        float mc[4], sums[4], alpha[4];
        #pragma unroll
        for (int r = 0; r < 4; ++r) {
            float v = fmaxf(fmaxf(S[0][r], S[1][r]), fmaxf(S[2][r], S[3][r]));
            v = fmaxf(v, __shfl_xor(v, 1, 64));
            v = fmaxf(v, __shfl_xor(v, 2, 64));
            v = fmaxf(v, __shfl_xor(v, 4, 64));
            v = fmaxf(v, __shfl_xor(v, 8, 64));
            mc[r] = v;
        }
        #pragma unroll
        for (int r = 0; r < 4; ++r) {
            const float mn = fmaxf(m[r], mc[r]);
            alpha[r] = __expf(m[r] - mn);
            m[r] = mn;
            sums[r] = 0.f;
        }
        #pragma unroll
        for (int tile = 0; tile < 4; ++tile) {
            #pragma unroll
            for (int r = 0; r < 4; ++r) {
                const float p = __expf(S[tile][r] - m[r]);
                S[tile][r] = p;
                sums[r] += p;
            }
        }
        #pragma unroll
        for (int r = 0; r < 4; ++r) {
            float v = sums[r];
            v += __shfl_xor(v, 1, 64);
            v += __shfl_xor(v, 2, 64);
            v += __shfl_xor(v, 4, 64);
            v += __shfl_xor(v, 8, 64);
            l[r] = l[r] * alpha[r] + v;
        }
        #pragma unroll
        for (int tile = 0; tile < 4; ++tile)
            #pragma unroll
            for (int r = 0; r < 4; ++r) O[tile][r] *= alpha[r];

        #pragma unroll
        for (int tile = 0; tile < 4; ++tile) {
            const int chunkcol = tile * 2 + (row16 >> 3);
            #pragma unroll
            for (int r = 0; r < 4; ++r) {
                const int prow = quad * 4 + r;
                const int addr = w * 1024 + prow * 64 +
                                 ((chunkcol ^ (prow & 7)) * 8) + (row16 & 7);
                const float p = S[tile][r];
                const h16 hi = f2h(p);
                pH[addr] = hi;
                pL[addr] = f2h(p - (float)hi);
            }
        }

        #pragma unroll
        for (int kk = 0; kk < 2; ++kk) {
            const int poff = w * 1024 + row16 * 64 + (((kk * 4 + quad) ^ (row16 & 7)) * 8);
            v8h pa = *(const v8h*)&pH[poff];
            v8h pb = *(const v8h*)&pL[poff];
            #pragma unroll
            for (int tile = 0; tile < 4; ++tile) {
                const int off = (tile * 16 + row16) * 64 + (((kk * 4 + quad) ^ (row16 & 7)) * 8);
                v8h vbh = *(const v8h*)&vh[off];
                v8h vbl = *(const v8h*)&vl[off];
                O[tile] = __builtin_amdgcn_mfma_f32_16x16x32_f16(pa, vbh, O[tile], 0, 0, 0);
                O[tile] = __builtin_amdgcn_mfma_f32_16x16x32_f16(pa, vbl, O[tile], 0, 0, 0);
                O[tile] = __builtin_amdgcn_mfma_f32_16x16x32_f16(pb, vbh, O[tile], 0, 0, 0);
            }
        }
    }

    #pragma unroll
    for (int tile = 0; tile < 4; ++tile) {
        const int dim = tile * 16 + row16;
        #pragma unroll
        for (int r = 0; r < 4; ++r) {
            const long grow = (long)bat * 256 + qc * 64 + w * 16 + quad * 4 + r;
            const float v = O[tile][r] / l[r];
            const long idx = grow * 512 + head * 64 + dim;
            const h16 hi = f2h(v);
            outbf[idx] = hi;
            outbf[idx + pl] = f2h(v - (float)hi);
        }
    }
}

// =====================================================================
// Pooled attention over distinct ctx entries. Block per (rb, head);
// 128 thr = 2 waves (one per bb). kvc3 rows: [rb*NMD + md][1024].
// =====================================================================
template <int M>
__global__ __launch_bounds__(128) void attn_pool_kernel(
    const float* __restrict__ qb, const float* __restrict__ kvc3,
    h16* __restrict__ outbf, long plane)
{
    const int rb = blockIdx.x >> 3;
    const int h = blockIdx.x & 7;
    __shared__ float k_lds[M * 66];
    __shared__ float v_lds[M * 66];
    __shared__ float q_lds[2 * 64];
    __shared__ float p_lds[2 * 64];
    const int t = threadIdx.x;
    const int g = rb >> 8, nn = rb & 255;

    for (int idx = t; idx < M * 64; idx += 128) {
        const int m = idx >> 6, d = idx & 63;
        const long base = ((long)rb * NMD + m) * 1024 + h * DH + d;
        k_lds[m * 66 + d] = kvc3[base];
        v_lds[m * 66 + d] = kvc3[base + 512];
    }
    {
        const int w = t >> 6, dd = t & 63;
        const long iq = (long)(g * 2 + w) * 256 + nn;
        q_lds[t] = qb[iq * Dm + h * DH + dd];
    }
    __syncthreads();

    const int w = t >> 6;
    const int lane = t & 63;
    float s = -1e30f;
    if (lane < M) {
        s = 0.f;
        const float* kr = &k_lds[lane * 66];
        const float* qr = &q_lds[w * 64];
        #pragma unroll
        for (int dd = 0; dd < 64; dd += 2) {
            s = fmaf(qr[dd], kr[dd], s);
            s = fmaf(qr[dd + 1], kr[dd + 1], s);
        }
    }
    float mx = s;
    #pragma unroll
    for (int off = 32; off > 0; off >>= 1) mx = fmaxf(mx, __shfl_xor(mx, off, 64));
    const float p = __expf(s - mx);
    float l = p;
    #pragma unroll
    for (int off = 32; off > 0; off >>= 1) l += __shfl_xor(l, off, 64);
    p_lds[w * 64 + lane] = p / l;

    float o = 0.f;
    const float* pr = &p_lds[w * 64];
    #pragma unroll
    for (int m = 0; m < M; ++m)
        o = fmaf(pr[m], v_lds[m * 66 + lane], o);

    const long iq = (long)(g * 2 + w) * 256 + nn;
    const long oidx = iq * Dm + h * DH + lane;
    const h16 hi = f2h(o);
    outbf[oidx] = hi;
    outbf[oidx + plane] = f2h(o - (float)hi);
}

// =====================================================================
__global__ void replicate_kernel(const float* __restrict__ src,
                                 float* __restrict__ tokens,
                                 h16* __restrict__ tokbf, long tpl)
{
    const int idx = blockIdx.x * blockDim.x + threadIdx.x;
    if (idx >= NTD * Dm) return;
    const float v = src[idx & (Bv * Nn_ * Dm - 1)];
    tokens[idx] = v;
    const h16 hi = f2h(v);
    tokbf[idx] = hi;
    tokbf[idx + tpl] = f2h(v - (float)hi);
}

// =====================================================================
extern "C" void kernel_launch(void* const* d_in, const int* in_sizes, int n_in,
                              void* d_out, int out_size, void* d_ws, size_t ws_size,
                              hipStream_t stream)
{
    const float* tok_in       = (const float*)d_in[0];
    const float* attn_norm_w  = (const float*)d_in[1];
    const float* attn_wq      = (const float*)d_in[2];
    const float* attn_wkv     = (const float*)d_in[3];
    const float* attn_wo      = (const float*)d_in[4];
    const float* ff_norm_w    = (const float*)d_in[5];
    const float* ff_keys_w    = (const float*)d_in[6];
    const float* ff_keys_b    = (const float*)d_in[7];
    const float* ff_values_w  = (const float*)d_in[8];
    const float* ff_values_b  = (const float*)d_in[9];
    const float* res_norm_w   = (const float*)d_in[10];
    const float* res_wq       = (const float*)d_in[11];
    const float* res_wkv      = (const float*)d_in[12];
    const float* res_wo       = (const float*)d_in[13];

    float* ws = (float*)d_ws;
    float* kvc3   = ws;                                  // 512*14*1024
    float* tokens = kvc3 + 512L * NMD * 1024;            // NTD*512
    float* qbuf   = tokens + (long)NTD * Dm;             // NTD*512
    float* hbuf   = qbuf + (long)NTD * Dm;               // NTD*2816
    float* biasWf = hbuf + (long)NTD * NFF;              // 1024

    h16* us = (h16*)(biasWf + 1024);
    const long apl = (long)NTD * Dm;
    const long hpl = (long)NTD * KFF;
    const long vtpl = (long)NTD * Dm;
    const long w1 = 512L * 512, w2 = 1024L * 512, w3 = (long)NFF * 512;
    const long w5 = (long)KFF * 512;
    const long wa_pl = 1024L * 512;
    const long wf_pl = 1024L * KFF;
    h16* tokbf = us; us += 2 * apl;
    h16* xa    = us; us += 2 * apl;
    h16* xf    = us; us += 2 * apl;
    h16* xr    = us; us += 2 * apl;
    h16* abf   = us; us += 2 * apl;
    h16* hbf   = us; us += 2 * hpl;
    h16* qhl   = us; us += 2 * apl;
    h16* khl   = us; us += 2 * apl;
    h16* vtb   = us; us += 2 * vtpl;
    h16* wqb   = us; us += 2 * w1;
    h16* wkvb  = us; us += 2 * w2;
    h16* fkb   = us; us += 2 * w3;
    h16* rqb   = us; us += 2 * w1;
    h16* rkvb  = us; us += 2 * w2;
    h16* rob   = us; us += 2 * w1;
    h16* woTb  = us; us += 2 * w1;     // attn_wo^T
    h16* fvwTb = us; us += 2 * w5;     // ff_values_w^T, padded to KFF rows
    h16* Wab   = us; us += 2 * wa_pl;  // res_wkv @ attn_wo   [1024, 512]
    h16* Wfb   = us; us += 2 * wf_pl;  // res_wkv @ ff_values [1024, KFF]

    auto cvtw = [&](const float* src, int Ms, int Ks, int Kp, int Mpad,
                    h16* dst, long pl) {
        const int tot = Mpad * Kp;
        cvt_hilo<<<(tot + 255) / 256, 256, 0, stream>>>(src, Ms, Ks, Kp, dst, pl, tot);
    };
    cvtw(attn_wq,   512,  512, 512, 512,  wqb,  w1);
    cvtw(attn_wkv,  1024, 512, 512, 1024, wkvb, w2);
    cvtw(ff_keys_w, DFF2, 512, 512, NFF,  fkb,  w3);
    cvtw(res_wq,    512,  512, 512, 512,  rqb,  w1);
    cvtw(res_wkv,   1024, 512, 512, 1024, rkvb, w2);
    cvtw(res_wo,    512,  512, 512, 512,  rob,  w1);
    cvt_hilo_T<<<(512 * 512 + 255) / 256, 256, 0, stream>>>(attn_wo, 512, 512, woTb, w1, 512 * 512);
    cvt_hilo_T<<<((int)w5 + 255) / 256, 256, 0, stream>>>(ff_values_w, 512, DFF, fvwTb, w5, (int)w5);
    fold_bias<<<4, 256, 0, stream>>>(res_wkv, ff_values_b, biasWf);

    auto mk = [](const h16* A, long Apl, int lda,
                 const h16* W, long Wpl, int ldw,
                 const float* bias, float* C, int ldc, int Nd,
                 h16* Cbf, long bfpl, int mbase, int K,
                 int mode, int nbx) -> GDesc {
        GDesc d;
        d.A = A; d.Apl = Apl; d.lda = lda;
        d.W = W; d.Wpl = Wpl; d.ldw = ldw;
        d.bias = bias; d.C = C; d.ldc = ldc; d.Nd = Nd;
        d.Cbf = Cbf; d.bfpl = bfpl; d.mbase = mbase; d.K = K;
        d.mode = mode; d.nbx = nbx;
        return d;
    };

    // ---- precompute folded weights: Wf (176 blocks) + Wa (64 blocks) ----
    {
        GDesc dWf = mk(rkvb, w2, 512, fvwTb, w5, 512, nullptr, nullptr, KFF, KFF,
                       Wfb, wf_pl, 0, 512, 1, 16);
        GDesc dWa = mk(rkvb, w2, 512, woTb, w1, 512, nullptr, nullptr, 512, 512,
                       Wab, wa_pl, 0, 512, 1, 16);
        mega_gemm<64><<<240, 256, 0, stream>>>(dWf, dWa, dWa, dWa, 176, 240, 240);
    }

    replicate_kernel<<<(NTD * Dm + 255) / 256, 256, 0, stream>>>(tok_in, tokens, tokbf, apl);

    for (int e = 0; e < 3; ++e) {
        rmsnorm3_bf<<<NTD, 256, 0, stream>>>(tokens, attn_norm_w, ff_norm_w, res_norm_w,
                                             xa, xf, xr, apl);
        // ---- B1: ffk(352) + wkv K/V^T(128) + wq(64) = 544 blocks ----
        {
            GDesc dffk = mk(xf,    apl, 512, fkb,  w3, 512, ff_keys_b, hbuf, NFF, DFF2,
                            nullptr, 0, 0, 512, 0, 16);
            GDesc dwkv = mk(tokbf, apl, 512, wkvb, w2, 512, nullptr, (float*)vtb, 1024, 1024,
                            khl, apl, 0, 512, 4, 16);
            GDesc dwq  = mk(xa,    apl, 512, wqb,  w1, 512, nullptr, nullptr, 512, 512,
                            qhl, apl, 0, 512, 1, 16);
            mega_gemm<64><<<544, 256, 0, stream>>>(dffk, dwkv, dwq, dwq, 352, 480, 544);
        }
        // ---- fused self-attention (128) + GLU (1024) ----
        attn_glu<<<1152, 256, 0, stream>>>(qhl, khl, vtb, apl, abf, hbuf, hbf, hpl);
        // ---- B2: ffv-kv(128) + wo-kv(128) + rq(64) [+ tok-kv(128) at e0] ----
        {
            GDesc dffvKV = mk(hbf, hpl, KFF, Wfb, wf_pl, KFF, biasWf, kvc3, 1024, 1024,
                              nullptr, 0, 2 + 2 * e, KFF, 3, 16);
            GDesc dwoKV  = mk(abf, apl, 512, Wab, wa_pl, 512, nullptr, kvc3, 1024, 1024,
                              nullptr, 0, 1 + 2 * e, 512, 3, 16);
            GDesc drq    = mk(xr, apl, 512, rqb, w1, 512, nullptr, qbuf, 512, 512,
                              nullptr, 0, 0, 512, 0, 16);
            if (e == 0) {
                GDesc dtokKV = mk(tokbf, apl, 512, rkvb, w2, 512, nullptr, kvc3, 1024, 1024,
                                  nullptr, 0, 0, 512, 3, 16);
                mega_gemm<64><<<448, 256, 0, stream>>>(dffvKV, dwoKV, drq, dtokKV, 128, 256, 320);
            } else {
                mega_gemm<64><<<320, 256, 0, stream>>>(dffvKV, dwoKV, drq, drq, 128, 256, 320);
            }
        }
        // ---- pooled attention ----
        if (e == 0)      attn_pool_kernel<6><<<512 * NH, 128, 0, stream>>>(qbuf, kvc3, abf, apl);
        else if (e == 1) attn_pool_kernel<10><<<512 * NH, 128, 0, stream>>>(qbuf, kvc3, abf, apl);
        else             attn_pool_kernel<14><<<512 * NH, 128, 0, stream>>>(qbuf, kvc3, abf, apl);
        // ---- B4: ro (BM=32, 128 blocks) ----
        {
            if (e < 2) {
                GDesc dro = mk(abf, apl, 512, rob, w1, 512, nullptr, tokens, 512, 512,
                               tokbf, apl, 0, 512, 2, 32);
                mega_gemm<32><<<128, 256, 0, stream>>>(dro, dro, dro, dro, 128, 128, 128);
            } else {
                GDesc dro = mk(abf, apl, 512, rob, w1, 512, nullptr, (float*)d_out, 512, 512,
                               nullptr, 0, 0, 512, 5, 32);
                mega_gemm<32><<<128, 256, 0, stream>>>(dro, dro, dro, dro, 128, 128, 128);
            }
        }
    }
}

// Round 12
// 466.992 us; speedup vs baseline: 2.1474x; 1.0502x over previous
//
#include <hip/hip_runtime.h>
#include <math.h>

// ---- problem constants ----
#define Dm   512
#define Nn_  256
#define Bv   2
#define NTD  1024          // dedup rows: (group g, batch bb, pos nn)
#define NH   8
#define DH   64
#define DFF  1365
#define DFF2 2730
#define KFF  1408
#define NFF  2816
#define NMD  14            // max distinct pooled-context entries
#define EPSR 1.1920929e-07f

typedef _Float16 h16;
typedef h16  v8h  __attribute__((ext_vector_type(8)));
typedef float v4f __attribute__((ext_vector_type(4)));

__device__ inline h16 f2h(float v) { return (h16)v; }

__device__ inline void glds16(const void* g, void* l) {
    __builtin_amdgcn_global_load_lds((const __attribute__((address_space(1))) void*)g,
                                     (__attribute__((address_space(3))) void*)l, 16, 0, 0);
}

// =====================================================================
// Multi-GEMM dispatcher (4 descriptors), fp16 3-term compensated,
// double-buffered LDS, templated tile BM x BN (BN in {64,128}).
// Optional per-row scale rss (folded RMSNorm) applied before bias.
// modes: 0 fp32 C; 1 fp16 hi/lo Cbf; 2 both; 3 pooled-ctx remap
// (md = mbase*2 + group); 4 attn KV split; 5 final 3-copy expand.
// =====================================================================
struct GDesc {
    const h16* A;
    const h16* W;
    const float* bias;
    const float* rss;
    float* C;
    h16* Cbf;
    long Apl, Wpl, bfpl;
    int lda, ldw, ldc, Nd, mbase, K, mode, nbx;
};

template <int BM, int BN>
__global__ __launch_bounds__(256) void mega_gemm(GDesc d0, GDesc d1, GDesc d2, GDesc d3,
                                                 int n0, int n01, int n012)
{
    constexpr int NWN = (BN == 128) ? 2 : 1;   // n-dir waves
    constexpr int NWM = 4 / NWN;               // m-dir waves
    constexpr int MI = BM / (16 * NWM);        // 16-row tiles per wave
    constexpr int ABUF = BM * 32;
    constexpr int WBUFh = BN * 32;
    constexpr int BUF = 2 * ABUF + 2 * WBUFh;
    constexpr int ASEG = BM / 16;
    constexpr int WSEG = BN / 16;
    constexpr int NSEG = 2 * ASEG + 2 * WSEG;
    __shared__ h16 lds[2 * BUF];

    GDesc d; int lb = blockIdx.x;
    if (lb < n0) d = d0;
    else if (lb < n01) { d = d1; lb -= n0; }
    else if (lb < n012) { d = d2; lb -= n01; }
    else { d = d3; lb -= n012; }
    const int bx = lb % d.nbx;
    const int by = lb / d.nbx;

    const int tid = threadIdx.x;
    const int wid = tid >> 6;
    const int lane = tid & 63;
    const int wm = wid / NWN, wn = wid % NWN;
    const int row16 = lane & 15, quad = lane >> 4;
    const long i0 = (long)bx * BM;
    const long j0 = (long)by * BN;
    const int l4 = lane >> 2;
    const int l2s = ((lane & 3) ^ (l4 & 3)) * 8;
    const int ksw = (quad ^ (row16 & 3)) * 8;

    auto stage = [&](int k0, h16* buf) {
        #pragma unroll
        for (int s = 0; s < NSEG / 4; ++s) {
            const int sg = wid * (NSEG / 4) + s;
            const h16* src;
            int dst;
            if (sg < ASEG) {
                src = d.A + (i0 + sg * 16 + l4) * (long)d.lda + k0 + l2s;
                dst = sg * 512;
            } else if (sg < 2 * ASEG) {
                const int r = sg - ASEG;
                src = d.A + d.Apl + (i0 + r * 16 + l4) * (long)d.lda + k0 + l2s;
                dst = ABUF + r * 512;
            } else if (sg < 2 * ASEG + WSEG) {
                const int r = sg - 2 * ASEG;
                src = d.W + (j0 + r * 16 + l4) * (long)d.ldw + k0 + l2s;
                dst = 2 * ABUF + r * 512;
            } else {
                const int r = sg - 2 * ASEG - WSEG;
                src = d.W + d.Wpl + (j0 + r * 16 + l4) * (long)d.ldw + k0 + l2s;
                dst = 2 * ABUF + WBUFh + r * 512;
            }
            glds16(src, &buf[dst]);
        }
    };

    v4f acc[MI][4];
    #pragma unroll
    for (int a = 0; a < MI; ++a)
        #pragma unroll
        for (int b = 0; b < 4; ++b) acc[a][b] = (v4f){0.f, 0.f, 0.f, 0.f};

    stage(0, lds);
    int cur = 0;
    for (int k0 = 0; k0 < d.K; k0 += 32) {
        __syncthreads();
        h16* cbuf = &lds[cur * BUF];
        if (k0 + 32 < d.K) stage(k0 + 32, &lds[(cur ^ 1) * BUF]);

        v8h af[MI], al[MI];
        #pragma unroll
        for (int mi = 0; mi < MI; ++mi) {
            const int aoff = (wm * (16 * MI) + mi * 16 + row16) * 32 + ksw;
            af[mi] = *(const v8h*)&cbuf[aoff];
            al[mi] = *(const v8h*)&cbuf[ABUF + aoff];
        }
        #pragma unroll
        for (int nj = 0; nj < 4; ++nj) {
            const int boff = (wn * 64 + nj * 16 + row16) * 32 + ksw;
            v8h bh = *(const v8h*)&cbuf[2 * ABUF + boff];
            v8h bl = *(const v8h*)&cbuf[2 * ABUF + WBUFh + boff];
            #pragma unroll
            for (int mi = 0; mi < MI; ++mi) {
                acc[mi][nj] = __builtin_amdgcn_mfma_f32_16x16x32_f16(af[mi], bh, acc[mi][nj], 0, 0, 0);
                acc[mi][nj] = __builtin_amdgcn_mfma_f32_16x16x32_f16(af[mi], bl, acc[mi][nj], 0, 0, 0);
                acc[mi][nj] = __builtin_amdgcn_mfma_f32_16x16x32_f16(al[mi], bh, acc[mi][nj], 0, 0, 0);
            }
        }
        cur ^= 1;
    }

    #pragma unroll
    for (int nj = 0; nj < 4; ++nj) {
        const int col = (int)j0 + wn * 64 + nj * 16 + row16;
        if (col < d.Nd) {
            const float bv = d.bias ? d.bias[col] : 0.f;
            #pragma unroll
            for (int mi = 0; mi < MI; ++mi) {
                #pragma unroll
                for (int r = 0; r < 4; ++r) {
                    const long row = i0 + wm * (16 * MI) + mi * 16 + quad * 4 + r;
                    float v = acc[mi][nj][r];
                    if (d.rss) v *= d.rss[(int)row];
                    v += bv;
                    if (d.mode == 0) {
                        d.C[row * (long)d.ldc + col] = v;
                    } else if (d.mode == 1) {
                        const long idx = row * (long)d.ldc + col;
                        const h16 hi = f2h(v);
                        d.Cbf[idx] = hi; d.Cbf[idx + d.bfpl] = f2h(v - (float)hi);
                    } else if (d.mode == 2) {
                        const long idx = row * (long)d.ldc + col;
                        d.C[idx] = v;
                        const h16 hi = f2h(v);
                        d.Cbf[idx] = hi; d.Cbf[idx + d.bfpl] = f2h(v - (float)hi);
                    } else if (d.mode == 3) {
                        const int rr = (int)row & 1023;
                        const int md = d.mbase * 2 + (rr >> 9);
                        const long orow = (long)(((rr >> 8) & 1) * 256 + (rr & 255)) * NMD + md;
                        d.C[orow * 1024 + col] = v;
                    } else if (d.mode == 4) {
                        const h16 hi = f2h(v);
                        const h16 lo = f2h(v - (float)hi);
                        if (col < 512) {
                            const long idx = row * 512 + col;
                            d.Cbf[idx] = hi; d.Cbf[idx + d.bfpl] = lo;
                        } else {
                            const int c = col - 512;
                            const int bh_ = ((int)(row >> 8)) * 8 + (c >> 6);
                            const long idx = (((long)bh_ * 64 + (c & 63)) << 8) + (row & 255);
                            h16* vtp = (h16*)d.C;
                            vtp[idx] = hi; vtp[idx + d.bfpl] = lo;
                        }
                    } else {
                        const int g = (int)(row >> 9), bb = ((int)row >> 8) & 1, nn = (int)row & 255;
                        #pragma unroll
                        for (int rep = 0; rep < 3; ++rep) {
                            const long orow = (long)(((g * 3 + rep) * 2 + bb) * 256 + nn);
                            d.C[orow * (long)d.ldc + col] = v;
                        }
                    }
                }
            }
        }
    }
}

// =====================================================================
// Fused setup: all weight converts (+norm folds, transposes), bias fold,
// token replicate. One dispatch, compile-time block ranges.
// =====================================================================
struct SetupP {
    const float *attn_wq, *attn_wkv, *ff_keys_w, *res_wq, *res_wkv, *res_wo,
                *attn_wo, *ff_values_w, *ff_values_b,
                *attn_norm_w, *ff_norm_w, *res_norm_w, *tok_in;
    h16 *wqb, *wkvb, *fkb, *rqb, *rkvb, *rob, *woTb, *fvwTb, *tokbf;
    float *biasWf, *tokens;
};

__device__ inline void cvt_dev(int idx, const float* x, int Ms, int Ks, int Kp,
                               h16* y, long plane, const float* cs)
{
    const int row = idx / Kp;
    const int col = idx - row * Kp;
    float v = (row < Ms && col < Ks) ? x[(long)row * Ks + col] : 0.f;
    if (cs) v *= cs[col];
    const h16 hi = f2h(v);
    y[idx] = hi;
    y[idx + plane] = f2h(v - (float)hi);
}

__device__ inline void cvtT_dev(int idx, const float* x, int R, int C,
                                h16* y, long plane)
{
    const int row = idx / R;        // src col
    const int col = idx - row * R;  // src row
    const float v = (row < C) ? x[(long)col * C + row] : 0.f;
    const h16 hi = f2h(v);
    y[idx] = hi;
    y[idx + plane] = f2h(v - (float)hi);
}

__global__ __launch_bounds__(256) void setup_all(SetupP p)
{
    long b = blockIdx.x;
    const int t = threadIdx.x;
    if (b < 1024) { cvt_dev((int)(b * 256 + t), p.attn_wq, 512, 512, 512, p.wqb, 512L * 512, p.attn_norm_w); return; }
    b -= 1024;
    if (b < 2048) { cvt_dev((int)(b * 256 + t), p.attn_wkv, 1024, 512, 512, p.wkvb, 1024L * 512, nullptr); return; }
    b -= 2048;
    if (b < 5632) { cvt_dev((int)(b * 256 + t), p.ff_keys_w, DFF2, 512, 512, p.fkb, (long)NFF * 512, p.ff_norm_w); return; }
    b -= 5632;
    if (b < 1024) { cvt_dev((int)(b * 256 + t), p.res_wq, 512, 512, 512, p.rqb, 512L * 512, p.res_norm_w); return; }
    b -= 1024;
    if (b < 2048) { cvt_dev((int)(b * 256 + t), p.res_wkv, 1024, 512, 512, p.rkvb, 1024L * 512, nullptr); return; }
    b -= 2048;
    if (b < 1024) { cvt_dev((int)(b * 256 + t), p.res_wo, 512, 512, 512, p.rob, 512L * 512, nullptr); return; }
    b -= 1024;
    if (b < 1024) { cvtT_dev((int)(b * 256 + t), p.attn_wo, 512, 512, p.woTb, 512L * 512); return; }
    b -= 1024;
    if (b < 2816) { cvtT_dev((int)(b * 256 + t), p.ff_values_w, 512, DFF, p.fvwTb, (long)KFF * 512); return; }
    b -= 2816;
    if (b < 4) {
        const int n = (int)(b * 256 + t);
        if (n < 1024) {
            float s = 0.f;
            const float* row = p.res_wkv + (long)n * 512;
            for (int dd = 0; dd < 512; ++dd) s = fmaf(row[dd], p.ff_values_b[dd], s);
            p.biasWf[n] = s;
        }
        return;
    }
    b -= 4;
    {   // replicate tokens -> dedup tokens fp32 + tokbf hi/lo
        const int idx = (int)(b * 256 + t);
        const float v = p.tok_in[idx & (Bv * Nn_ * Dm - 1)];
        p.tokens[idx] = v;
        const h16 hi = f2h(v);
        p.tokbf[idx] = hi;
        p.tokbf[idx + (long)NTD * Dm] = f2h(v - (float)hi);
    }
}
#define SETUP_BLOCKS 18692

// =====================================================================
// Per-row RMSNorm scale only: rs[r] = rsqrt(mean(x_r^2)+eps). Grid 256.
// =====================================================================
__global__ __launch_bounds__(256) void rs_kernel(const float* __restrict__ x,
                                                 float* __restrict__ rs)
{
    const int r = blockIdx.x * 4 + (threadIdx.x >> 6);
    const int lane = threadIdx.x & 63;
    const float* row = x + (long)r * Dm + lane * 8;
    float ss = 0.f;
    #pragma unroll
    for (int i = 0; i < 8; i += 4) {
        const float4 v = *(const float4*)(row + i);
        ss += v.x * v.x + v.y * v.y + v.z * v.z + v.w * v.w;
    }
    #pragma unroll
    for (int off = 32; off > 0; off >>= 1) ss += __shfl_xor(ss, off, 64);
    if (lane == 0) rs[r] = rsqrtf(ss * (1.f / 512.f) + EPSR);
}

// =====================================================================
// Fused MFMA flash self-attention (blocks 0..127) + GLU-GELU (128..1151).
// =====================================================================
__global__ __launch_bounds__(256) void attn_glu(
    const h16* __restrict__ qhl, const h16* __restrict__ khl,
    const h16* __restrict__ vtb, long pl, h16* __restrict__ outbf,
    const float* __restrict__ hbuf, h16* __restrict__ hbf, long hpl)
{
    if (blockIdx.x >= 128) {
        const int r = blockIdx.x - 128;
        const float* row = hbuf + (long)r * NFF;
        for (int c = threadIdx.x; c < KFF; c += 256) {
            float v = 0.f;
            if (c < DFF) {
                const float sim = row[c];
                const float g = row[c + DFF];
                v = sim * (0.5f * g * (1.f + erff(g * 0.70710678118654752440f)));
            }
            const long idx = (long)r * KFF + c;
            const h16 hi = f2h(v);
            hbf[idx] = hi;
            hbf[idx + hpl] = f2h(v - (float)hi);
        }
        return;
    }

    __shared__ h16 kh[4096], kl[4096], vh[4096], vl[4096];
    __shared__ h16 pH[4 * 1024], pL[4 * 1024];

    const int bat = blockIdx.x >> 5;
    const int head = (blockIdx.x >> 2) & 7;
    const int qc = blockIdx.x & 3;
    const int t = threadIdx.x;
    const int w = t >> 6, lane = t & 63;
    const int row16 = lane & 15, quad = lane >> 4;

    v8h qh[2], ql[2];
    {
        const long qrow = (long)bat * 256 + qc * 64 + w * 16 + row16;
        const h16* qp = qhl + qrow * 512 + head * 64 + quad * 8;
        qh[0] = *(const v8h*)qp;        qh[1] = *(const v8h*)(qp + 32);
        ql[0] = *(const v8h*)(qp + pl); ql[1] = *(const v8h*)(qp + pl + 32);
    }

    v4f O[4];
    #pragma unroll
    for (int i = 0; i < 4; ++i) O[i] = (v4f){0.f, 0.f, 0.f, 0.f};
    float m[4] = {-1e30f, -1e30f, -1e30f, -1e30f};
    float l[4] = {0.f, 0.f, 0.f, 0.f};

    const int sj = t >> 3;
    const int sc = t & 7;
    const long kbase = ((long)bat * 256) * 512 + head * 64;
    const long vbase = ((long)(bat * 8 + head) * 64) << 8;

    for (int jc = 0; jc < 256; jc += 64) {
        __syncthreads();
        #pragma unroll
        for (int rep = 0; rep < 2; ++rep) {
            const int row = sj + rep * 32;
            const int dsw = row * 64 + ((sc ^ (row & 7)) * 8);
            const h16* ks = khl + kbase + (long)(jc + row) * 512 + sc * 8;
            const h16* vs = vtb + vbase + ((long)row << 8) + jc + sc * 8;
            *(v8h*)&kh[dsw] = *(const v8h*)ks;
            *(v8h*)&kl[dsw] = *(const v8h*)(ks + pl);
            *(v8h*)&vh[dsw] = *(const v8h*)vs;
            *(v8h*)&vl[dsw] = *(const v8h*)(vs + pl);
        }
        __syncthreads();

        v4f S[4];
        #pragma unroll
        for (int i = 0; i < 4; ++i) S[i] = (v4f){0.f, 0.f, 0.f, 0.f};
        #pragma unroll
        for (int kk = 0; kk < 2; ++kk) {
            #pragma unroll
            for (int tile = 0; tile < 4; ++tile) {
                const int off = (tile * 16 + row16) * 64 + (((kk * 4 + quad) ^ (row16 & 7)) * 8);
                v8h bh = *(const v8h*)&kh[off];
                v8h bl = *(const v8h*)&kl[off];
                S[tile] = __builtin_amdgcn_mfma_f32_16x16x32_f16(qh[kk], bh, S[tile], 0, 0, 0);
                S[tile] = __builtin_amdgcn_mfma_f32_16x16x32_f16(qh[kk], bl, S[tile], 0, 0, 0);
                S[tile] = __builtin_amdgcn_mfma_f32_16x16x32_f16(ql[kk], bh, S[tile], 0, 0, 0);
            }
        }

        float mc[4], sums[4], alpha[4];
        #pragma unroll
        for (int r = 0; r < 4; ++r) {
            float v = fmaxf(fmaxf(S[0][r], S[1][r]), fmaxf(S[2][r], S[3][r]));
            v = fmaxf(v, __shfl_xor(v, 1, 64));
            v = fmaxf(v, __shfl_xor(v, 2, 64));
            v = fmaxf(v, __shfl_xor(v, 4, 64));
            v = fmaxf(v, __shfl_xor(v, 8, 64));
            mc[r] = v;
        }
        #pragma unroll
        for (int r = 0; r < 4; ++r) {
            const float mn = fmaxf(m[r], mc[r]);
            alpha[r] = __expf(m[r] - mn);
            m[r] = mn;
            sums[r] = 0.f;
        }
        #pragma unroll
        for (int tile = 0; tile < 4; ++tile) {
            #pragma unroll
            for (int r = 0; r < 4; ++r) {
                const float p = __expf(S[tile][r] - m[r]);
                S[tile][r] = p;
                sums[r] += p;
            }
        }
        #pragma unroll
        for (int r = 0; r < 4; ++r) {
            float v = sums[r];
            v += __shfl_xor(v, 1, 64);
            v += __shfl_xor(v, 2, 64);
            v += __shfl_xor(v, 4, 64);
            v += __shfl_xor(v, 8, 64);
            l[r] = l[r] * alpha[r] + v;
        }
        #pragma unroll
        for (int tile = 0; tile < 4; ++tile)
            #pragma unroll
            for (int r = 0; r < 4; ++r) O[tile][r] *= alpha[r];

        #pragma unroll
        for (int tile = 0; tile < 4; ++tile) {
            const int chunkcol = tile * 2 + (row16 >> 3);
            #pragma unroll
            for (int r = 0; r < 4; ++r) {
                const int prow = quad * 4 + r;
                const int addr = w * 1024 + prow * 64 +
                                 ((chunkcol ^ (prow & 7)) * 8) + (row16 & 7);
                const float p = S[tile][r];
                const h16 hi = f2h(p);
                pH[addr] = hi;
                pL[addr] = f2h(p - (float)hi);
            }
        }

        #pragma unroll
        for (int kk = 0; kk < 2; ++kk) {
            const int poff = w * 1024 + row16 * 64 + (((kk * 4 + quad) ^ (row16 & 7)) * 8);
            v8h pa = *(const v8h*)&pH[poff];
            v8h pb = *(const v8h*)&pL[poff];
            #pragma unroll
            for (int tile = 0; tile < 4; ++tile) {
                const int off = (tile * 16 + row16) * 64 + (((kk * 4 + quad) ^ (row16 & 7)) * 8);
                v8h vbh = *(const v8h*)&vh[off];
                v8h vbl = *(const v8h*)&vl[off];
                O[tile] = __builtin_amdgcn_mfma_f32_16x16x32_f16(pa, vbh, O[tile], 0, 0, 0);
                O[tile] = __builtin_amdgcn_mfma_f32_16x16x32_f16(pa, vbl, O[tile], 0, 0, 0);
                O[tile] = __builtin_amdgcn_mfma_f32_16x16x32_f16(pb, vbh, O[tile], 0, 0, 0);
            }
        }
    }

    #pragma unroll
    for (int tile = 0; tile < 4; ++tile) {
        const int dim = tile * 16 + row16;
        #pragma unroll
        for (int r = 0; r < 4; ++r) {
            const long grow = (long)bat * 256 + qc * 64 + w * 16 + quad * 4 + r;
            const float v = O[tile][r] / l[r];
            const long idx = grow * 512 + head * 64 + dim;
            const h16 hi = f2h(v);
            outbf[idx] = hi;
            outbf[idx + pl] = f2h(v - (float)hi);
        }
    }
}

// =====================================================================
// Pooled attention over distinct ctx entries. Block per (rb, head);
// 128 thr = 2 waves (one per bb). kvc3 rows: [rb*NMD + md][1024].
// =====================================================================
template <int M>
__global__ __launch_bounds__(128) void attn_pool_kernel(
    const float* __restrict__ qb, const float* __restrict__ kvc3,
    h16* __restrict__ outbf, long plane)
{
    const int rb = blockIdx.x >> 3;
    const int h = blockIdx.x & 7;
    __shared__ float k_lds[M * 66];
    __shared__ float v_lds[M * 66];
    __shared__ float q_lds[2 * 64];
    __shared__ float p_lds[2 * 64];
    const int t = threadIdx.x;
    const int g = rb >> 8, nn = rb & 255;

    for (int idx = t; idx < M * 64; idx += 128) {
        const int m = idx >> 6, d = idx & 63;
        const long base = ((long)rb * NMD + m) * 1024 + h * DH + d;
        k_lds[m * 66 + d] = kvc3[base];
        v_lds[m * 66 + d] = kvc3[base + 512];
    }
    {
        const int w = t >> 6, dd = t & 63;
        const long iq = (long)(g * 2 + w) * 256 + nn;
        q_lds[t] = qb[iq * Dm + h * DH + dd];
    }
    __syncthreads();

    const int w = t >> 6;
    const int lane = t & 63;
    float s = -1e30f;
    if (lane < M) {
        s = 0.f;
        const float* kr = &k_lds[lane * 66];
        const float* qr = &q_lds[w * 64];
        #pragma unroll
        for (int dd = 0; dd < 64; dd += 2) {
            s = fmaf(qr[dd], kr[dd], s);
            s = fmaf(qr[dd + 1], kr[dd + 1], s);
        }
    }
    float mx = s;
    #pragma unroll
    for (int off = 32; off > 0; off >>= 1) mx = fmaxf(mx, __shfl_xor(mx, off, 64));
    const float p = __expf(s - mx);
    float l = p;
    #pragma unroll
    for (int off = 32; off > 0; off >>= 1) l += __shfl_xor(l, off, 64);
    p_lds[w * 64 + lane] = p / l;

    float o = 0.f;
    const float* pr = &p_lds[w * 64];
    #pragma unroll
    for (int m = 0; m < M; ++m)
        o = fmaf(pr[m], v_lds[m * 66 + lane], o);

    const long iq = (long)(g * 2 + w) * 256 + nn;
    const long oidx = iq * Dm + h * DH + lane;
    const h16 hi = f2h(o);
    outbf[oidx] = hi;
    outbf[oidx + plane] = f2h(o - (float)hi);
}

// =====================================================================
extern "C" void kernel_launch(void* const* d_in, const int* in_sizes, int n_in,
                              void* d_out, int out_size, void* d_ws, size_t ws_size,
                              hipStream_t stream)
{
    const float* tok_in       = (const float*)d_in[0];
    const float* attn_norm_w  = (const float*)d_in[1];
    const float* attn_wq      = (const float*)d_in[2];
    const float* attn_wkv     = (const float*)d_in[3];
    const float* attn_wo      = (const float*)d_in[4];
    const float* ff_norm_w    = (const float*)d_in[5];
    const float* ff_keys_w    = (const float*)d_in[6];
    const float* ff_keys_b    = (const float*)d_in[7];
    const float* ff_values_w  = (const float*)d_in[8];
    const float* ff_values_b  = (const float*)d_in[9];
    const float* res_norm_w   = (const float*)d_in[10];
    const float* res_wq       = (const float*)d_in[11];
    const float* res_wkv      = (const float*)d_in[12];
    const float* res_wo       = (const float*)d_in[13];

    float* ws = (float*)d_ws;
    float* kvc3   = ws;                                  // 512*14*1024
    float* tokens = kvc3 + 512L * NMD * 1024;            // NTD*512
    float* qbuf   = tokens + (long)NTD * Dm;             // NTD*512
    float* hbuf   = qbuf + (long)NTD * Dm;               // NTD*2816
    float* biasWf = hbuf + (long)NTD * NFF;              // 1024
    float* rsbuf  = biasWf + 1024;                       // 1024

    h16* us = (h16*)(rsbuf + 1024);
    const long apl = (long)NTD * Dm;
    const long hpl = (long)NTD * KFF;
    const long w1 = 512L * 512, w2 = 1024L * 512, w3 = (long)NFF * 512;
    const long w5 = (long)KFF * 512;
    const long wa_pl = 1024L * 512;
    const long wf_pl = 1024L * KFF;
    h16* tokbf = us; us += 2 * apl;
    h16* abf   = us; us += 2 * apl;
    h16* hbf   = us; us += 2 * hpl;
    h16* qhl   = us; us += 2 * apl;
    h16* khl   = us; us += 2 * apl;
    h16* vtb   = us; us += 2 * apl;
    h16* wqb   = us; us += 2 * w1;
    h16* wkvb  = us; us += 2 * w2;
    h16* fkb   = us; us += 2 * w3;
    h16* rqb   = us; us += 2 * w1;
    h16* rkvb  = us; us += 2 * w2;
    h16* rob   = us; us += 2 * w1;
    h16* woTb  = us; us += 2 * w1;
    h16* fvwTb = us; us += 2 * w5;
    h16* Wab   = us; us += 2 * wa_pl;
    h16* Wfb   = us; us += 2 * wf_pl;

    // ---- fused setup (weights + folds + replicate), one dispatch ----
    {
        SetupP p;
        p.attn_wq = attn_wq; p.attn_wkv = attn_wkv; p.ff_keys_w = ff_keys_w;
        p.res_wq = res_wq; p.res_wkv = res_wkv; p.res_wo = res_wo;
        p.attn_wo = attn_wo; p.ff_values_w = ff_values_w; p.ff_values_b = ff_values_b;
        p.attn_norm_w = attn_norm_w; p.ff_norm_w = ff_norm_w; p.res_norm_w = res_norm_w;
        p.tok_in = tok_in;
        p.wqb = wqb; p.wkvb = wkvb; p.fkb = fkb; p.rqb = rqb; p.rkvb = rkvb;
        p.rob = rob; p.woTb = woTb; p.fvwTb = fvwTb; p.tokbf = tokbf;
        p.biasWf = biasWf; p.tokens = tokens;
        setup_all<<<SETUP_BLOCKS, 256, 0, stream>>>(p);
    }

    auto mk = [](const h16* A, long Apl, int lda,
                 const h16* W, long Wpl, int ldw,
                 const float* bias, const float* rss,
                 float* C, int ldc, int Nd,
                 h16* Cbf, long bfpl, int mbase, int K,
                 int mode, int nbx) -> GDesc {
        GDesc d;
        d.A = A; d.Apl = Apl; d.lda = lda;
        d.W = W; d.Wpl = Wpl; d.ldw = ldw;
        d.bias = bias; d.rss = rss; d.C = C; d.ldc = ldc; d.Nd = Nd;
        d.Cbf = Cbf; d.bfpl = bfpl; d.mbase = mbase; d.K = K;
        d.mode = mode; d.nbx = nbx;
        return d;
    };

    // ---- precompute folded weights: Wf (352) + Wa (128) ----
    {
        GDesc dWf = mk(rkvb, w2, 512, fvwTb, w5, 512, nullptr, nullptr, nullptr, KFF, KFF,
                       Wfb, wf_pl, 0, 512, 1, 16);
        GDesc dWa = mk(rkvb, w2, 512, woTb, w1, 512, nullptr, nullptr, nullptr, 512, 512,
                       Wab, wa_pl, 0, 512, 1, 16);
        mega_gemm<64, 64><<<480, 256, 0, stream>>>(dWf, dWa, dWa, dWa, 352, 480, 480);
    }

    for (int e = 0; e < 3; ++e) {
        rs_kernel<<<256, 256, 0, stream>>>(tokens, rsbuf);
        // ---- B1: ffk(704) + wkv K/V^T(256) + wq(128) = 1088 blocks ----
        {
            GDesc dffk = mk(tokbf, apl, 512, fkb,  w3, 512, ff_keys_b, rsbuf, hbuf, NFF, DFF2,
                            nullptr, 0, 0, 512, 0, 16);
            GDesc dwkv = mk(tokbf, apl, 512, wkvb, w2, 512, nullptr, nullptr, (float*)vtb, 1024, 1024,
                            khl, apl, 0, 512, 4, 16);
            GDesc dwq  = mk(tokbf, apl, 512, wqb,  w1, 512, nullptr, rsbuf, nullptr, 512, 512,
                            qhl, apl, 0, 512, 1, 16);
            mega_gemm<64, 64><<<1088, 256, 0, stream>>>(dffk, dwkv, dwq, dwq, 704, 960, 1088);
        }
        // ---- fused self-attention (128) + GLU (1024) ----
        attn_glu<<<1152, 256, 0, stream>>>(qhl, khl, vtb, apl, abf, hbuf, hbf, hpl);
        // ---- B2: ffv-kv(256) + wo-kv(256) + rq(128) [+ tok-kv(256) at e0] ----
        {
            GDesc dffvKV = mk(hbf, hpl, KFF, Wfb, wf_pl, KFF, biasWf, nullptr, kvc3, 1024, 1024,
                              nullptr, 0, 2 + 2 * e, KFF, 3, 16);
            GDesc dwoKV  = mk(abf, apl, 512, Wab, wa_pl, 512, nullptr, nullptr, kvc3, 1024, 1024,
                              nullptr, 0, 1 + 2 * e, 512, 3, 16);
            GDesc drq    = mk(tokbf, apl, 512, rqb, w1, 512, nullptr, rsbuf, qbuf, 512, 512,
                              nullptr, 0, 0, 512, 0, 16);
            if (e == 0) {
                GDesc dtokKV = mk(tokbf, apl, 512, rkvb, w2, 512, nullptr, nullptr, kvc3, 1024, 1024,
                                  nullptr, 0, 0, 512, 3, 16);
                mega_gemm<64, 64><<<896, 256, 0, stream>>>(dffvKV, dwoKV, drq, dtokKV, 256, 512, 640);
            } else {
                mega_gemm<64, 64><<<640, 256, 0, stream>>>(dffvKV, dwoKV, drq, drq, 256, 512, 640);
            }
        }
        // ---- pooled attention ----
        if (e == 0)      attn_pool_kernel<6><<<512 * NH, 128, 0, stream>>>(qbuf, kvc3, abf, apl);
        else if (e == 1) attn_pool_kernel<10><<<512 * NH, 128, 0, stream>>>(qbuf, kvc3, abf, apl);
        else             attn_pool_kernel<14><<<512 * NH, 128, 0, stream>>>(qbuf, kvc3, abf, apl);
        // ---- B4: ro (BM=32, BN=128, 128 blocks) ----
        {
            if (e < 2) {
                GDesc dro = mk(abf, apl, 512, rob, w1, 512, nullptr, nullptr, tokens, 512, 512,
                               tokbf, apl, 0, 512, 2, 32);
                mega_gemm<32, 128><<<128, 256, 0, stream>>>(dro, dro, dro, dro, 128, 128, 128);
            } else {
                GDesc dro = mk(abf, apl, 512, rob, w1, 512, nullptr, nullptr, (float*)d_out, 512, 512,
                               nullptr, 0, 0, 512, 5, 32);
                mega_gemm<32, 128><<<128, 256, 0, stream>>>(dro, dro, dro, dro, 128, 128, 128);
            }
        }
    }
}